// Round 15
// baseline (945.770 us; speedup 1.0000x reference)
//
#include <hip/hip_runtime.h>
#include <hip/hip_bf16.h>
#include <cstdint>

#define SEQ   16384
#define ED    1152
#define NH    16
#define HD    72
#define NSEG  8
#define SEGLEN 2048
#define QKVN  3456
#define VTROWS 80

typedef __bf16 bf16x8 __attribute__((ext_vector_type(8)));
typedef float  f32x4  __attribute__((ext_vector_type(4)));
typedef __hip_bfloat16 bf16;

__device__ __forceinline__ unsigned short f2bfbits(float f) {
  bf16 h = __float2bfloat16(f);
  return __builtin_bit_cast(unsigned short, h);
}

__device__ __forceinline__ float fexp2(float x) {
#if __has_builtin(__builtin_amdgcn_exp2f)
  return __builtin_amdgcn_exp2f(x);
#else
  return exp2f(x);
#endif
}

__device__ __forceinline__ void gload_lds16(const void* g, void* l) {
  __builtin_amdgcn_global_load_lds(
      (__attribute__((address_space(1))) void*)(void*)g,
      (__attribute__((address_space(3))) void*)l, 16, 0, 0);
}

// ---------------- prep kernels ----------------
__global__ __launch_bounds__(256) void cvt_f32_bf16(const float* __restrict__ in,
                                                    bf16* __restrict__ out, int n4) {
  int i = blockIdx.x * 256 + threadIdx.x;
  if (i >= n4) return;
  float4 v = reinterpret_cast<const float4*>(in)[i];
  ushort4 o;
  o.x = f2bfbits(v.x); o.y = f2bfbits(v.y); o.z = f2bfbits(v.z); o.w = f2bfbits(v.w);
  reinterpret_cast<ushort4*>(out)[i] = o;
}

// ---------------- GEMM: C[M][N] = A[M][K] * B[N][K]^T + bias, m97-style ----------------
__global__ __launch_bounds__(256) void gemm_bt(const bf16* __restrict__ A,
                                               const bf16* __restrict__ B,
                                               const float* __restrict__ bias,
                                               void* __restrict__ Cout,
                                               int M, int N, int K, int out_bf16) {
  __shared__ __align__(16) bf16 As[128 * 32];
  __shared__ __align__(16) bf16 Bs[128 * 32];
  const int nt   = N >> 7;
  const int bm   = blockIdx.x / nt;
  const int bn   = blockIdx.x % nt;
  const int tid  = threadIdx.x;
  const int lane = tid & 63;
  const int wave = tid >> 6;
  const int wr   = wave >> 1, wc = wave & 1;

  const bf16* Ab = A + (size_t)(bm * 128) * K;
  const bf16* Bb = B + (size_t)(bn * 128) * K;
  const int r0 = tid >> 2;
  const int c0 = (tid & 3) << 3;

  char* AsB = (char*)As;
  char* BsB = (char*)Bs;
  const int ldsoff = wave * 1024;

  const int row15 = lane & 15;
  const int koff  = (lane >> 4) << 3;

  f32x4 acc[4][4] = {};

  for (int k0 = 0; k0 < K; k0 += 32) {
    gload_lds16(Ab + (size_t)r0 * K + k0 + c0,        AsB + ldsoff);
    gload_lds16(Ab + (size_t)(r0 + 64) * K + k0 + c0, AsB + 4096 + ldsoff);
    gload_lds16(Bb + (size_t)r0 * K + k0 + c0,        BsB + ldsoff);
    gload_lds16(Bb + (size_t)(r0 + 64) * K + k0 + c0, BsB + 4096 + ldsoff);
    __syncthreads();
    bf16x8 a[4], b[4];
#pragma unroll
    for (int mi = 0; mi < 4; ++mi)
      a[mi] = *reinterpret_cast<const bf16x8*>(&As[(wr * 64 + mi * 16 + row15) * 32 + koff]);
#pragma unroll
    for (int ni = 0; ni < 4; ++ni)
      b[ni] = *reinterpret_cast<const bf16x8*>(&Bs[(wc * 64 + ni * 16 + row15) * 32 + koff]);
#pragma unroll
    for (int mi = 0; mi < 4; ++mi)
#pragma unroll
      for (int ni = 0; ni < 4; ++ni)
        acc[mi][ni] = __builtin_amdgcn_mfma_f32_16x16x32_bf16(a[mi], b[ni], acc[mi][ni], 0, 0, 0);
    __syncthreads();
  }

  const int crow = bm * 128 + wr * 64 + (lane >> 4) * 4;
  const int ccol = bn * 128 + wc * 64 + row15;
#pragma unroll
  for (int mi = 0; mi < 4; ++mi)
#pragma unroll
    for (int ni = 0; ni < 4; ++ni) {
      const int col = ccol + ni * 16;
      const float bv = bias[col];
#pragma unroll
      for (int r = 0; r < 4; ++r) {
        const int row = crow + mi * 16 + r;
        float v = acc[mi][ni][r] + bv;
        if (out_bf16)
          reinterpret_cast<bf16*>(Cout)[(size_t)row * N + col] = __float2bfloat16(v);
        else
          reinterpret_cast<float*>(Cout)[(size_t)row * N + col] = v;
      }
    }
}

// ---------------- RoPE in-place on qkv [s][3456] ----------------
__global__ __launch_bounds__(256) void rope_inplace(bf16* __restrict__ qkv,
                                                    const float* __restrict__ ang) {
  const int s = blockIdx.x;
  bf16* row = qkv + (size_t)s * QKVN;
  for (int i = threadIdx.x; i < 2 * NH * 36; i += 256) {
    int t   = i / (NH * 36);
    int rem = i - t * (NH * 36);
    int h   = rem / 36;
    int d2  = rem - h * 36;
    float a  = ang[s * 36 + d2];
    float cs = cosf(a), sn = sinf(a);
    bf16* p = row + t * ED + h * HD + d2;
    float x1 = __bfloat162float(p[0]);
    float x2 = __bfloat162float(p[36]);
    p[0]  = __float2bfloat16(x1 * cs - x2 * sn);
    p[36] = __float2bfloat16(x2 * cs + x1 * sn);
  }
}

// ---------------- V transpose: qkv V columns -> V^T[h][d][s], d rows 0..71 data,
// row 72 = ones (row-sum column), 73..79 = 0. Reuses verified stage_v rotation math.
__global__ __launch_bounds__(256, 4) void transpose_v(const bf16* __restrict__ qkv,
                                                      bf16* __restrict__ vt) {
  const int h  = blockIdx.x & 15;
  const int st = blockIdx.x >> 4;
  const int s0 = st * 64;
  const int tid = threadIdx.x;
  __shared__ __align__(16) bf16 Lt[72 * 72];  // [d][s-rot], stride 72, rotated cols

  const bf16* src = qkv + (size_t)s0 * QKVN + 2 * ED + h * HD;
  for (int c = tid; c < 576; c += 256) {
    int j = c / 9, m9 = c - j * 9;
    int d0 = m9 << 3;
    int jj = (j + (m9 << 3)) & 63;
    bf16x8 v = *reinterpret_cast<const bf16x8*>(src + (size_t)j * QKVN + d0);
    const unsigned short* u = reinterpret_cast<const unsigned short*>(&v);
#pragma unroll
    for (int e = 0; e < 8; ++e)
      Lt[(d0 + e) * 72 + jj] = __builtin_bit_cast(bf16, u[e]);
  }
  __syncthreads();

  bf16x8 ones8, zero8 = {};
  {
    unsigned short ob = f2bfbits(1.0f);
#pragma unroll
    for (int e = 0; e < 8; ++e) ones8[e] = __builtin_bit_cast(__bf16, ob);
  }
  bf16* dst = vt + (size_t)(h * VTROWS) * SEQ + s0;
  for (int c = tid; c < VTROWS * 8; c += 256) {
    int d = c >> 3, sc = c & 7;
    bf16x8 v;
    if (d < 72) {
      int col = (((sc + (d >> 3)) << 3)) & 63;   // inverse of the write rotation
      v = *reinterpret_cast<const bf16x8*>(&Lt[d * 72 + col]);
    } else {
      v = (d == 72) ? ones8 : zero8;
    }
    *reinterpret_cast<bf16x8*>(dst + (size_t)d * SEQ + (sc << 3)) = v;
  }
}

// ---------------- flash attention v12: BARRIER-FREE ----------------
// Ps is wave-private (each wave writes/reads only its own 32 rows) and V comes
// pre-transposed from global (V^T, L2-served like K) -> no Vt LDS, no stage_v,
// ZERO __syncthreads in the k-loop. Register structure identical to R14 (no spill).
__global__ __launch_bounds__(256, 4) void attn_vt(const bf16* __restrict__ qkv,
                                                  const bf16* __restrict__ vt,
                                                  bf16* __restrict__ ctx) {
  const int blk  = blockIdx.x;
  const int qt   = (blk >> 3) & 15;
  const int g    = (((blk >> 7) & 15) << 3) | (blk & 7);
  const int head = g & 15;
  const int seg  = g >> 4;
  const int q0   = seg * SEGLEN + qt * 128;

  const int tid = threadIdx.x, lane = tid & 63, w = tid >> 6;
  const int row15 = lane & 15, hi = lane >> 4, koff = hi << 3;

  __shared__ __align__(16) bf16 Ps[128 * 72];  // [q][kv] stride 72; per-wave exclusive rows

  const bf16* Qg  = qkv + (size_t)q0 * QKVN + head * HD;
  const bf16* Kg  = qkv + (size_t)(seg * SEGLEN) * QKVN + ED + head * HD;
  const bf16* Vth = vt + (size_t)(head * VTROWS) * SEQ + seg * SEGLEN;

  const bf16x8 zero8 = {};
  bf16x8 aq[2][3];
#pragma unroll
  for (int m = 0; m < 2; ++m) {
    const bf16* qrow = Qg + (size_t)(w * 32 + m * 16 + row15) * QKVN;
    aq[m][0] = *reinterpret_cast<const bf16x8*>(qrow + koff);
    aq[m][1] = *reinterpret_cast<const bf16x8*>(qrow + 32 + koff);
    aq[m][2] = (hi == 0) ? *reinterpret_cast<const bf16x8*>(qrow + 64) : zero8;
  }

  f32x4 oacc[2][5] = {};
  const float c2 = 0.11785113019775793f * 1.4426950408889634f;  // scale * log2(e)

  for (int kt = 0; kt < SEGLEN / 64; ++kt) {
    // ---- S = Q K^T (K direct from global) ----
    f32x4 s[2][4] = {};
    const bf16* Kt = Kg + (size_t)kt * 64 * QKVN;
    __builtin_amdgcn_s_setprio(1);
#pragma unroll
    for (int ks = 0; ks < 2; ++ks) {
#pragma unroll
      for (int n = 0; n < 4; ++n) {
        bf16x8 bk = *reinterpret_cast<const bf16x8*>(Kt + (size_t)(n * 16 + row15) * QKVN + ks * 32 + koff);
        s[0][n] = __builtin_amdgcn_mfma_f32_16x16x32_bf16(aq[0][ks], bk, s[0][n], 0, 0, 0);
        s[1][n] = __builtin_amdgcn_mfma_f32_16x16x32_bf16(aq[1][ks], bk, s[1][n], 0, 0, 0);
      }
    }
#pragma unroll
    for (int n = 0; n < 4; ++n) {
      bf16x8 bk = (hi == 0) ? *reinterpret_cast<const bf16x8*>(Kt + (size_t)(n * 16 + row15) * QKVN + 64) : zero8;
      s[0][n] = __builtin_amdgcn_mfma_f32_16x16x32_bf16(aq[0][2], bk, s[0][n], 0, 0, 0);
      s[1][n] = __builtin_amdgcn_mfma_f32_16x16x32_bf16(aq[1][2], bk, s[1][n], 0, 0, 0);
    }
    __builtin_amdgcn_s_setprio(0);

    // ---- fixed-shift softmax -> own wave's Ps rows (wave-local, lgkmcnt-ordered) ----
    const int prow_base = w * 32 + hi * 4;
#pragma unroll
    for (int m = 0; m < 2; ++m)
#pragma unroll
      for (int n = 0; n < 4; ++n)
#pragma unroll
        for (int r = 0; r < 4; ++r) {
          float p = fexp2(fmaf(s[m][n][r], c2, -4.0f));
          Ps[(prow_base + m * 16 + r) * 72 + n * 16 + row15] =
              __builtin_bit_cast(bf16, f2bfbits(p));
        }

    // ---- O += P V : A from own Ps rows, B direct from V^T global ----
    const bf16* Vkt = Vth + kt * 64;
    __builtin_amdgcn_s_setprio(1);
#pragma unroll
    for (int ks = 0; ks < 2; ++ks) {
      bf16x8 ap0 = *reinterpret_cast<const bf16x8*>(&Ps[(w * 32 + row15) * 72 + ks * 32 + koff]);
      bf16x8 ap1 = *reinterpret_cast<const bf16x8*>(&Ps[(w * 32 + 16 + row15) * 72 + ks * 32 + koff]);
#pragma unroll
      for (int n = 0; n < 5; ++n) {
        const int vrow = n * 16 + row15;
        bf16x8 bv = *reinterpret_cast<const bf16x8*>(Vkt + (size_t)vrow * SEQ + ks * 32 + koff);
        oacc[0][n] = __builtin_amdgcn_mfma_f32_16x16x32_bf16(ap0, bv, oacc[0][n], 0, 0, 0);
        oacc[1][n] = __builtin_amdgcn_mfma_f32_16x16x32_bf16(ap1, bv, oacc[1][n], 0, 0, 0);
      }
    }
    __builtin_amdgcn_s_setprio(0);
  }

  // ---- epilogue: l = oacc[m][4] at row15==8 (V^T ones-row d=72); normalize & store ----
#pragma unroll
  for (int m = 0; m < 2; ++m) {
#pragma unroll
    for (int r = 0; r < 4; ++r) {
      float l = __shfl(oacc[m][4][r], (lane & 48) + 8);
      float inv = 1.0f / l;
#pragma unroll
      for (int n = 0; n < 5; ++n) {
        const int d = n * 16 + row15;
        if (d < HD) {
          const int row = q0 + w * 32 + m * 16 + hi * 4 + r;
          ctx[(size_t)row * ED + head * HD + d] = __float2bfloat16(oacc[m][n][r] * inv);
        }
      }
    }
  }
}

// ---------------- flash attention v11 (R14) — fallback when ws too small ----------------
__global__ __launch_bounds__(256, 4) void attn(const bf16* __restrict__ qkv,
                                               bf16* __restrict__ ctx) {
  const int blk  = blockIdx.x;
  const int qt   = (blk >> 3) & 15;
  const int g    = (((blk >> 7) & 15) << 3) | (blk & 7);
  const int head = g & 15;
  const int seg  = g >> 4;
  const int q0   = seg * SEGLEN + qt * 128;

  const int tid = threadIdx.x, lane = tid & 63, w = tid >> 6;
  const int row15 = lane & 15, hi = lane >> 4, koff = hi << 3;

  __shared__ __align__(16) bf16 Vt[80 * 72];
  __shared__ __align__(16) bf16 Ps[128 * 72];

  const bf16* Qg = qkv + (size_t)q0 * QKVN + head * HD;
  const bf16* Kg = qkv + (size_t)(seg * SEGLEN) * QKVN + ED + head * HD;
  const bf16* Vg = qkv + (size_t)(seg * SEGLEN) * QKVN + 2 * ED + head * HD;

  {
    const bf16 one  = __float2bfloat16(1.0f);
    const bf16 zerob = __float2bfloat16(0.0f);
    for (int e = tid; e < 8 * 72; e += 256)
      Vt[72 * 72 + e] = (e < 72) ? one : zerob;
  }

  const bf16x8 zero8 = {};
  bf16x8 aq[2][3];
#pragma unroll
  for (int m = 0; m < 2; ++m) {
    const bf16* qrow = Qg + (size_t)(w * 32 + m * 16 + row15) * QKVN;
    aq[m][0] = *reinterpret_cast<const bf16x8*>(qrow + koff);
    aq[m][1] = *reinterpret_cast<const bf16x8*>(qrow + 32 + koff);
    aq[m][2] = (hi == 0) ? *reinterpret_cast<const bf16x8*>(qrow + 64) : zero8;
  }

  f32x4 oacc[2][5] = {};
  const float c2 = 0.11785113019775793f * 1.4426950408889634f;

  auto stage_v = [&](int kt2) {
    const bf16* src0 = Vg + (size_t)kt2 * 64 * QKVN;
    for (int c = tid; c < 576; c += 256) {
      int j = c / 9, m9 = c - j * 9;
      int d0 = m9 << 3;
      int jj = (j + (m9 << 3)) & 63;
      bf16x8 v = *reinterpret_cast<const bf16x8*>(src0 + (size_t)j * QKVN + d0);
      const unsigned short* u = reinterpret_cast<const unsigned short*>(&v);
#pragma unroll
      for (int e = 0; e < 8; ++e)
        Vt[(d0 + e) * 72 + jj] = __builtin_bit_cast(bf16, u[e]);
    }
  };

  auto qkt_soft = [&](int kt2) {
    f32x4 s[2][4] = {};
    const bf16* Kt = Kg + (size_t)kt2 * 64 * QKVN;
    __builtin_amdgcn_s_setprio(1);
#pragma unroll
    for (int ks = 0; ks < 2; ++ks) {
#pragma unroll
      for (int n = 0; n < 4; ++n) {
        bf16x8 bk = *reinterpret_cast<const bf16x8*>(Kt + (size_t)(n * 16 + row15) * QKVN + ks * 32 + koff);
        s[0][n] = __builtin_amdgcn_mfma_f32_16x16x32_bf16(aq[0][ks], bk, s[0][n], 0, 0, 0);
        s[1][n] = __builtin_amdgcn_mfma_f32_16x16x32_bf16(aq[1][ks], bk, s[1][n], 0, 0, 0);
      }
    }
#pragma unroll
    for (int n = 0; n < 4; ++n) {
      bf16x8 bk = (hi == 0) ? *reinterpret_cast<const bf16x8*>(Kt + (size_t)(n * 16 + row15) * QKVN + 64) : zero8;
      s[0][n] = __builtin_amdgcn_mfma_f32_16x16x32_bf16(aq[0][2], bk, s[0][n], 0, 0, 0);
      s[1][n] = __builtin_amdgcn_mfma_f32_16x16x32_bf16(aq[1][2], bk, s[1][n], 0, 0, 0);
    }
    __builtin_amdgcn_s_setprio(0);
    const int prow_base = w * 32 + hi * 4;
#pragma unroll
    for (int m = 0; m < 2; ++m)
#pragma unroll
      for (int n = 0; n < 4; ++n)
#pragma unroll
        for (int r = 0; r < 4; ++r) {
          float p = fexp2(fmaf(s[m][n][r], c2, -4.0f));
          Ps[(prow_base + m * 16 + r) * 72 + n * 16 + row15] =
              __builtin_bit_cast(bf16, f2bfbits(p));
        }
  };

  auto pv = [&]() {
    __builtin_amdgcn_s_setprio(1);
#pragma unroll
    for (int ks = 0; ks < 2; ++ks) {
      bf16x8 ap0 = *reinterpret_cast<const bf16x8*>(&Ps[(w * 32 + row15) * 72 + ks * 32 + koff]);
      bf16x8 ap1 = *reinterpret_cast<const bf16x8*>(&Ps[(w * 32 + 16 + row15) * 72 + ks * 32 + koff]);
#pragma unroll
      for (int n = 0; n < 5; ++n) {
        const int vrow = n * 16 + row15;
        const int col = (ks * 32 + (hi << 3) + ((vrow >> 3) << 3)) & 63;
        bf16x8 bv = *reinterpret_cast<const bf16x8*>(&Vt[vrow * 72 + col]);
        oacc[0][n] = __builtin_amdgcn_mfma_f32_16x16x32_bf16(ap0, bv, oacc[0][n], 0, 0, 0);
        oacc[1][n] = __builtin_amdgcn_mfma_f32_16x16x32_bf16(ap1, bv, oacc[1][n], 0, 0, 0);
      }
    }
    __builtin_amdgcn_s_setprio(0);
  };

  stage_v(0);
  qkt_soft(0);
  for (int kt = 0; kt < SEGLEN / 64; ++kt) {
    __syncthreads();
    pv();
    __syncthreads();
    if (kt < SEGLEN / 64 - 1) {
      stage_v(kt + 1);
      qkt_soft(kt + 1);
    }
  }

#pragma unroll
  for (int m = 0; m < 2; ++m) {
#pragma unroll
    for (int r = 0; r < 4; ++r) {
      float l = __shfl(oacc[m][4][r], (lane & 48) + 8);
      float inv = 1.0f / l;
#pragma unroll
      for (int n = 0; n < 5; ++n) {
        const int d = n * 16 + row15;
        if (d < HD) {
          const int row = q0 + w * 32 + m * 16 + hi * 4 + r;
          ctx[(size_t)row * ED + head * HD + d] = __float2bfloat16(oacc[m][n][r] * inv);
        }
      }
    }
  }
}

// ---------------- launch ----------------
extern "C" void kernel_launch(void* const* d_in, const int* in_sizes, int n_in,
                              void* d_out, int out_size, void* d_ws, size_t ws_size,
                              hipStream_t stream) {
  const float* hidden = (const float*)d_in[0];
  const float* qkv_w  = (const float*)d_in[1];
  const float* qkv_b  = (const float*)d_in[2];
  const float* out_w  = (const float*)d_in[3];
  const float* out_b  = (const float*)d_in[4];
  const float* rope   = (const float*)d_in[5];

  const size_t SZ_QKV = (size_t)SEQ * QKVN * 2;
  const size_t SZ_X   = (size_t)SEQ * ED * 2;
  const size_t SZ_W   = (size_t)QKVN * ED * 2;
  const size_t SZ_VT  = (size_t)NH * VTROWS * SEQ * 2;
  const size_t NEED   = SZ_QKV + SZ_X + SZ_W;
  if (ws_size < NEED) return;
  const bool use_vt = (ws_size >= NEED + SZ_VT);

  char* ws = (char*)d_ws;
  bf16* qkvbf = (bf16*)(ws);
  bf16* Xbf   = (bf16*)(ws + SZ_QKV);
  bf16* Wbf   = (bf16*)(ws + SZ_QKV + SZ_X);
  bf16* vtb   = (bf16*)(ws + NEED);

  cvt_f32_bf16<<<(SEQ * ED / 4 + 255) / 256, 256, 0, stream>>>(hidden, Xbf, SEQ * ED / 4);
  cvt_f32_bf16<<<(QKVN * ED / 4 + 255) / 256, 256, 0, stream>>>(qkv_w, Wbf, QKVN * ED / 4);

  gemm_bt<<<(SEQ / 128) * (QKVN / 128), 256, 0, stream>>>(Xbf, Wbf, qkv_b, qkvbf,
                                                          SEQ, QKVN, ED, 1);

  cvt_f32_bf16<<<(ED * ED / 4 + 255) / 256, 256, 0, stream>>>(out_w, Wbf, ED * ED / 4);

  rope_inplace<<<SEQ, 256, 0, stream>>>(qkvbf, rope);

  if (use_vt) {
    transpose_v<<<NH * (SEQ / 64), 256, 0, stream>>>(qkvbf, vtb);
    attn_vt<<<NSEG * NH * (SEGLEN / 128), 256, 0, stream>>>(qkvbf, vtb, Xbf);
  } else {
    attn<<<NSEG * NH * (SEGLEN / 128), 256, 0, stream>>>(qkvbf, Xbf);
  }

  gemm_bt<<<(SEQ / 128) * (ED / 128), 256, 0, stream>>>(Xbf, Wbf, out_b, d_out,
                                                        SEQ, ED, ED, 0);
}

// Round 16
// 798.946 us; speedup vs baseline: 1.1838x; 1.1838x over previous
//
#include <hip/hip_runtime.h>
#include <hip/hip_bf16.h>
#include <cstdint>

#define SEQ   16384
#define ED    1152
#define NH    16
#define HD    72
#define NSEG  8
#define SEGLEN 2048
#define QKVN  3456
#define NT    (SEGLEN / 64)
#define VBUF  (73 * 72)   // 2 ring buffers; pv over-reads rows 73..79 into slack (unused lanes)

typedef __bf16 bf16x8 __attribute__((ext_vector_type(8)));
typedef float  f32x4  __attribute__((ext_vector_type(4)));
typedef __hip_bfloat16 bf16;

__device__ __forceinline__ unsigned short f2bfbits(float f) {
  bf16 h = __float2bfloat16(f);
  return __builtin_bit_cast(unsigned short, h);
}

__device__ __forceinline__ float fexp2(float x) {
#if __has_builtin(__builtin_amdgcn_exp2f)
  return __builtin_amdgcn_exp2f(x);
#else
  return exp2f(x);
#endif
}

__device__ __forceinline__ void gload_lds16(const void* g, void* l) {
  __builtin_amdgcn_global_load_lds(
      (__attribute__((address_space(1))) void*)(void*)g,
      (__attribute__((address_space(3))) void*)l, 16, 0, 0);
}

// ---------------- prep kernels ----------------
__global__ __launch_bounds__(256) void cvt_f32_bf16(const float* __restrict__ in,
                                                    bf16* __restrict__ out, int n4) {
  int i = blockIdx.x * 256 + threadIdx.x;
  if (i >= n4) return;
  float4 v = reinterpret_cast<const float4*>(in)[i];
  ushort4 o;
  o.x = f2bfbits(v.x); o.y = f2bfbits(v.y); o.z = f2bfbits(v.z); o.w = f2bfbits(v.w);
  reinterpret_cast<ushort4*>(out)[i] = o;
}

// ---------------- GEMM: C[M][N] = A[M][K] * B[N][K]^T + bias, m97-style ----------------
__global__ __launch_bounds__(256) void gemm_bt(const bf16* __restrict__ A,
                                               const bf16* __restrict__ B,
                                               const float* __restrict__ bias,
                                               void* __restrict__ Cout,
                                               int M, int N, int K, int out_bf16) {
  __shared__ __align__(16) bf16 As[128 * 32];
  __shared__ __align__(16) bf16 Bs[128 * 32];
  const int nt   = N >> 7;
  const int bm   = blockIdx.x / nt;
  const int bn   = blockIdx.x % nt;
  const int tid  = threadIdx.x;
  const int lane = tid & 63;
  const int wave = tid >> 6;
  const int wr   = wave >> 1, wc = wave & 1;

  const bf16* Ab = A + (size_t)(bm * 128) * K;
  const bf16* Bb = B + (size_t)(bn * 128) * K;
  const int r0 = tid >> 2;
  const int c0 = (tid & 3) << 3;

  char* AsB = (char*)As;
  char* BsB = (char*)Bs;
  const int ldsoff = wave * 1024;

  const int row15 = lane & 15;
  const int koff  = (lane >> 4) << 3;

  f32x4 acc[4][4] = {};

  for (int k0 = 0; k0 < K; k0 += 32) {
    gload_lds16(Ab + (size_t)r0 * K + k0 + c0,        AsB + ldsoff);
    gload_lds16(Ab + (size_t)(r0 + 64) * K + k0 + c0, AsB + 4096 + ldsoff);
    gload_lds16(Bb + (size_t)r0 * K + k0 + c0,        BsB + ldsoff);
    gload_lds16(Bb + (size_t)(r0 + 64) * K + k0 + c0, BsB + 4096 + ldsoff);
    __syncthreads();
    bf16x8 a[4], b[4];
#pragma unroll
    for (int mi = 0; mi < 4; ++mi)
      a[mi] = *reinterpret_cast<const bf16x8*>(&As[(wr * 64 + mi * 16 + row15) * 32 + koff]);
#pragma unroll
    for (int ni = 0; ni < 4; ++ni)
      b[ni] = *reinterpret_cast<const bf16x8*>(&Bs[(wc * 64 + ni * 16 + row15) * 32 + koff]);
#pragma unroll
    for (int mi = 0; mi < 4; ++mi)
#pragma unroll
      for (int ni = 0; ni < 4; ++ni)
        acc[mi][ni] = __builtin_amdgcn_mfma_f32_16x16x32_bf16(a[mi], b[ni], acc[mi][ni], 0, 0, 0);
    __syncthreads();
  }

  const int crow = bm * 128 + wr * 64 + (lane >> 4) * 4;
  const int ccol = bn * 128 + wc * 64 + row15;
#pragma unroll
  for (int mi = 0; mi < 4; ++mi)
#pragma unroll
    for (int ni = 0; ni < 4; ++ni) {
      const int col = ccol + ni * 16;
      const float bv = bias[col];
#pragma unroll
      for (int r = 0; r < 4; ++r) {
        const int row = crow + mi * 16 + r;
        float v = acc[mi][ni][r] + bv;
        if (out_bf16)
          reinterpret_cast<bf16*>(Cout)[(size_t)row * N + col] = __float2bfloat16(v);
        else
          reinterpret_cast<float*>(Cout)[(size_t)row * N + col] = v;
      }
    }
}

// ---------------- RoPE in-place on qkv [s][3456] ----------------
__global__ __launch_bounds__(256) void rope_inplace(bf16* __restrict__ qkv,
                                                    const float* __restrict__ ang) {
  const int s = blockIdx.x;
  bf16* row = qkv + (size_t)s * QKVN;
  for (int i = threadIdx.x; i < 2 * NH * 36; i += 256) {
    int t   = i / (NH * 36);
    int rem = i - t * (NH * 36);
    int h   = rem / 36;
    int d2  = rem - h * 36;
    float a  = ang[s * 36 + d2];
    float cs = cosf(a), sn = sinf(a);
    bf16* p = row + t * ED + h * HD + d2;
    float x1 = __bfloat162float(p[0]);
    float x2 = __bfloat162float(p[36]);
    p[0]  = __float2bfloat16(x1 * cs - x2 * sn);
    p[36] = __float2bfloat16(x2 * cs + x1 * sn);
  }
}

// ---------------- flash attention v13 = R14 + ONE barrier/tile ----------------
// Insight: Ps is wave-private (each wave writes AND reads only its own 32 rows;
// program order suffices). Barriers only protect Vt -> 2-buffer Vt ring with
// schedule {qkt_soft(kt); BARRIER; pv(kt); stage_v(kt+1)} is race-free:
//   producer: stage_v(kt) ... BARRIER(kt) ... pv(kt)            (1 barrier between)
//   anti-dep: pv(kt) ... BARRIER(kt+1) ... stage_v(kt+2)        (1 barrier between)
// Buffers are 73 rows + shared 7-row slack (pv over-reads rows 73..79; those
// products land only in oacc lanes that are never stored).
__global__ __launch_bounds__(256, 4) void attn(const bf16* __restrict__ qkv,
                                               bf16* __restrict__ ctx) {
  const int blk  = blockIdx.x;
  // swizzle: all 16 q-tiles of one (seg,head) land on one XCD for K/V L2 locality
  const int qt   = (blk >> 3) & 15;
  const int g    = (((blk >> 7) & 15) << 3) | (blk & 7);
  const int head = g & 15;
  const int seg  = g >> 4;
  const int q0   = seg * SEGLEN + qt * 128;

  const int tid = threadIdx.x, lane = tid & 63, w = tid >> 6;
  const int row15 = lane & 15, hi = lane >> 4, koff = hi << 3;

  __shared__ __align__(16) bf16 Vt[2 * VBUF + 7 * 72];  // 2 ring bufs + slack tail
  __shared__ __align__(16) bf16 Ps[128 * 72];           // per-wave exclusive rows

  const bf16* Qg = qkv + (size_t)q0 * QKVN + head * HD;
  const bf16* Kg = qkv + (size_t)(seg * SEGLEN) * QKVN + ED + head * HD;
  const bf16* Vg = qkv + (size_t)(seg * SEGLEN) * QKVN + 2 * ED + head * HD;

  // ones-row (d=72, the row-sum column) for both buffers; rows 73+ are don't-care
  {
    const bf16 one = __float2bfloat16(1.0f);
    for (int e = tid; e < 2 * 72; e += 256) {
      int b = e / 72, c = e - b * 72;
      Vt[b * VBUF + 72 * 72 + c] = one;
    }
  }

  // Q fragments in registers (2 m-frags x 3 k-chunks; chunk 2 = cols 64..71, low lanes only)
  const bf16x8 zero8 = {};
  bf16x8 aq[2][3];
#pragma unroll
  for (int m = 0; m < 2; ++m) {
    const bf16* qrow = Qg + (size_t)(w * 32 + m * 16 + row15) * QKVN;
    aq[m][0] = *reinterpret_cast<const bf16x8*>(qrow + koff);
    aq[m][1] = *reinterpret_cast<const bf16x8*>(qrow + 32 + koff);
    aq[m][2] = (hi == 0) ? *reinterpret_cast<const bf16x8*>(qrow + 64) : zero8;
  }

  f32x4 oacc[2][5] = {};
  const float c2 = 0.11785113019775793f * 1.4426950408889634f;  // scale * log2(e)

  // stage V tile kt2 into ring buffer (kt2&1) with column rotation jj=(j+8*(d>>3))&63
  auto stage_v = [&](int kt2) {
    bf16* dst = Vt + (kt2 & 1) * VBUF;
    const bf16* src0 = Vg + (size_t)kt2 * 64 * QKVN;
    for (int c = tid; c < 576; c += 256) {
      int j = c / 9, m9 = c - j * 9;
      int d0 = m9 << 3;
      int jj = (j + (m9 << 3)) & 63;
      bf16x8 v = *reinterpret_cast<const bf16x8*>(src0 + (size_t)j * QKVN + d0);
      const unsigned short* u = reinterpret_cast<const unsigned short*>(&v);
#pragma unroll
      for (int e = 0; e < 8; ++e)
        dst[(d0 + e) * 72 + jj] = __builtin_bit_cast(bf16, u[e]);
    }
  };

  // QK^T (K direct from global) + fixed-shift softmax + u16 P-stores (own rows)
  auto qkt_soft = [&](int kt2) {
    f32x4 s[2][4] = {};
    const bf16* Kt = Kg + (size_t)kt2 * 64 * QKVN;
    __builtin_amdgcn_s_setprio(1);
#pragma unroll
    for (int ks = 0; ks < 2; ++ks) {
#pragma unroll
      for (int n = 0; n < 4; ++n) {
        bf16x8 bk = *reinterpret_cast<const bf16x8*>(Kt + (size_t)(n * 16 + row15) * QKVN + ks * 32 + koff);
        s[0][n] = __builtin_amdgcn_mfma_f32_16x16x32_bf16(aq[0][ks], bk, s[0][n], 0, 0, 0);
        s[1][n] = __builtin_amdgcn_mfma_f32_16x16x32_bf16(aq[1][ks], bk, s[1][n], 0, 0, 0);
      }
    }
#pragma unroll
    for (int n = 0; n < 4; ++n) {
      bf16x8 bk = (hi == 0) ? *reinterpret_cast<const bf16x8*>(Kt + (size_t)(n * 16 + row15) * QKVN + 64) : zero8;
      s[0][n] = __builtin_amdgcn_mfma_f32_16x16x32_bf16(aq[0][2], bk, s[0][n], 0, 0, 0);
      s[1][n] = __builtin_amdgcn_mfma_f32_16x16x32_bf16(aq[1][2], bk, s[1][n], 0, 0, 0);
    }
    __builtin_amdgcn_s_setprio(0);
    const int prow_base = w * 32 + hi * 4;
#pragma unroll
    for (int m = 0; m < 2; ++m)
#pragma unroll
      for (int n = 0; n < 4; ++n)
#pragma unroll
        for (int r = 0; r < 4; ++r) {
          float p = fexp2(fmaf(s[m][n][r], c2, -4.0f));
          Ps[(prow_base + m * 16 + r) * 72 + n * 16 + row15] =
              __builtin_bit_cast(bf16, f2bfbits(p));
        }
  };

  auto pv = [&](int kt2) {
    const bf16* vb = Vt + (kt2 & 1) * VBUF;
    __builtin_amdgcn_s_setprio(1);
#pragma unroll
    for (int ks = 0; ks < 2; ++ks) {
      bf16x8 ap0 = *reinterpret_cast<const bf16x8*>(&Ps[(w * 32 + row15) * 72 + ks * 32 + koff]);
      bf16x8 ap1 = *reinterpret_cast<const bf16x8*>(&Ps[(w * 32 + 16 + row15) * 72 + ks * 32 + koff]);
#pragma unroll
      for (int n = 0; n < 5; ++n) {
        const int vrow = n * 16 + row15;
        const int col = (ks * 32 + (hi << 3) + ((vrow >> 3) << 3)) & 63;
        bf16x8 bv = *reinterpret_cast<const bf16x8*>(&vb[vrow * 72 + col]);
        oacc[0][n] = __builtin_amdgcn_mfma_f32_16x16x32_bf16(ap0, bv, oacc[0][n], 0, 0, 0);
        oacc[1][n] = __builtin_amdgcn_mfma_f32_16x16x32_bf16(ap1, bv, oacc[1][n], 0, 0, 0);
      }
    }
    __builtin_amdgcn_s_setprio(0);
  };

  // main loop: ONE barrier per tile
  stage_v(0);
  for (int kt = 0; kt < NT; ++kt) {
    qkt_soft(kt);          // K->MFMA->softmax->own Ps rows (wave-local)
    __syncthreads();       // Vt[kt&1] staged by all waves (prev iter / prologue)
    pv(kt);                // read Vt[kt&1] + own Ps rows
    if (kt + 1 < NT) stage_v(kt + 1);  // write other buffer
  }

  // ---- epilogue: l = oacc[m][4] at row15==8; normalize & store ----
#pragma unroll
  for (int m = 0; m < 2; ++m) {
#pragma unroll
    for (int r = 0; r < 4; ++r) {
      float l = __shfl(oacc[m][4][r], (lane & 48) + 8);
      float inv = 1.0f / l;
#pragma unroll
      for (int n = 0; n < 5; ++n) {
        const int d = n * 16 + row15;
        if (d < HD) {
          const int row = q0 + w * 32 + m * 16 + hi * 4 + r;
          ctx[(size_t)row * ED + head * HD + d] = __float2bfloat16(oacc[m][n][r] * inv);
        }
      }
    }
  }
}

// ---------------- launch ----------------
extern "C" void kernel_launch(void* const* d_in, const int* in_sizes, int n_in,
                              void* d_out, int out_size, void* d_ws, size_t ws_size,
                              hipStream_t stream) {
  const float* hidden = (const float*)d_in[0];
  const float* qkv_w  = (const float*)d_in[1];
  const float* qkv_b  = (const float*)d_in[2];
  const float* out_w  = (const float*)d_in[3];
  const float* out_b  = (const float*)d_in[4];
  const float* rope   = (const float*)d_in[5];

  const size_t SZ_QKV = (size_t)SEQ * QKVN * 2;
  const size_t SZ_X   = (size_t)SEQ * ED * 2;
  const size_t SZ_W   = (size_t)QKVN * ED * 2;
  const size_t NEED   = SZ_QKV + SZ_X + SZ_W;
  if (ws_size < NEED) return;

  char* ws = (char*)d_ws;
  bf16* qkvbf = (bf16*)(ws);
  bf16* Xbf   = (bf16*)(ws + SZ_QKV);
  bf16* Wbf   = (bf16*)(ws + SZ_QKV + SZ_X);

  cvt_f32_bf16<<<(SEQ * ED / 4 + 255) / 256, 256, 0, stream>>>(hidden, Xbf, SEQ * ED / 4);
  cvt_f32_bf16<<<(QKVN * ED / 4 + 255) / 256, 256, 0, stream>>>(qkv_w, Wbf, QKVN * ED / 4);

  gemm_bt<<<(SEQ / 128) * (QKVN / 128), 256, 0, stream>>>(Xbf, Wbf, qkv_b, qkvbf,
                                                          SEQ, QKVN, ED, 1);

  cvt_f32_bf16<<<(ED * ED / 4 + 255) / 256, 256, 0, stream>>>(out_w, Wbf, ED * ED / 4);

  rope_inplace<<<SEQ, 256, 0, stream>>>(qkvbf, rope);

  attn<<<NSEG * NH * (SEGLEN / 128), 256, 0, stream>>>(qkvbf, Xbf);

  gemm_bt<<<(SEQ / 128) * (ED / 128), 256, 0, stream>>>(Xbf, Wbf, out_b, d_out,
                                                        SEQ, ED, ED, 0);
}

// Round 17
// 576.679 us; speedup vs baseline: 1.6400x; 1.3854x over previous
//
#include <hip/hip_runtime.h>
#include <hip/hip_bf16.h>
#include <cstdint>

#define SEQ   16384
#define ED    1152
#define NH    16
#define HD    72
#define NSEG  8
#define SEGLEN 2048
#define QKVN  3456
#define NT    (SEGLEN / 64)

typedef __bf16 bf16x8 __attribute__((ext_vector_type(8)));
typedef float  f32x4  __attribute__((ext_vector_type(4)));
typedef __hip_bfloat16 bf16;

__device__ __forceinline__ unsigned short f2bfbits(float f) {
  bf16 h = __float2bfloat16(f);
  return __builtin_bit_cast(unsigned short, h);
}

__device__ __forceinline__ float fexp2(float x) {
#if __has_builtin(__builtin_amdgcn_exp2f)
  return __builtin_amdgcn_exp2f(x);
#else
  return exp2f(x);
#endif
}

__device__ __forceinline__ void gload_lds16(const void* g, void* l) {
  __builtin_amdgcn_global_load_lds(
      (__attribute__((address_space(1))) void*)(void*)g,
      (__attribute__((address_space(3))) void*)l, 16, 0, 0);
}

// ---------------- prep kernels ----------------
__global__ __launch_bounds__(256) void cvt_f32_bf16(const float* __restrict__ in,
                                                    bf16* __restrict__ out, int n4) {
  int i = blockIdx.x * 256 + threadIdx.x;
  if (i >= n4) return;
  float4 v = reinterpret_cast<const float4*>(in)[i];
  ushort4 o;
  o.x = f2bfbits(v.x); o.y = f2bfbits(v.y); o.z = f2bfbits(v.z); o.w = f2bfbits(v.w);
  reinterpret_cast<ushort4*>(out)[i] = o;
}

// ---------------- GEMM: C[M][N] = A[M][K] * B[N][K]^T + bias, m97-style + XCD swizzle ----
__global__ __launch_bounds__(256) void gemm_bt(const bf16* __restrict__ A,
                                               const bf16* __restrict__ B,
                                               const float* __restrict__ bias,
                                               void* __restrict__ Cout,
                                               int M, int N, int K, int out_bf16) {
  __shared__ __align__(16) bf16 As[128 * 32];
  __shared__ __align__(16) bf16 Bs[128 * 32];
  const int nt   = N >> 7;
  // bijective XCD swizzle (grid sizes here are multiples of 8)
  const int nwg  = gridDim.x;
  const int cpx  = nwg >> 3;
  const int bid  = blockIdx.x;
  const int swz  = (bid & 7) * cpx + (bid >> 3);
  const int bm   = swz / nt;
  const int bn   = swz % nt;
  const int tid  = threadIdx.x;
  const int lane = tid & 63;
  const int wave = tid >> 6;
  const int wr   = wave >> 1, wc = wave & 1;

  const bf16* Ab = A + (size_t)(bm * 128) * K;
  const bf16* Bb = B + (size_t)(bn * 128) * K;
  const int r0 = tid >> 2;
  const int c0 = (tid & 3) << 3;

  char* AsB = (char*)As;
  char* BsB = (char*)Bs;
  const int ldsoff = wave * 1024;

  const int row15 = lane & 15;
  const int koff  = (lane >> 4) << 3;

  f32x4 acc[4][4] = {};

  for (int k0 = 0; k0 < K; k0 += 32) {
    gload_lds16(Ab + (size_t)r0 * K + k0 + c0,        AsB + ldsoff);
    gload_lds16(Ab + (size_t)(r0 + 64) * K + k0 + c0, AsB + 4096 + ldsoff);
    gload_lds16(Bb + (size_t)r0 * K + k0 + c0,        BsB + ldsoff);
    gload_lds16(Bb + (size_t)(r0 + 64) * K + k0 + c0, BsB + 4096 + ldsoff);
    __syncthreads();
    bf16x8 a[4], b[4];
#pragma unroll
    for (int mi = 0; mi < 4; ++mi)
      a[mi] = *reinterpret_cast<const bf16x8*>(&As[(wr * 64 + mi * 16 + row15) * 32 + koff]);
#pragma unroll
    for (int ni = 0; ni < 4; ++ni)
      b[ni] = *reinterpret_cast<const bf16x8*>(&Bs[(wc * 64 + ni * 16 + row15) * 32 + koff]);
#pragma unroll
    for (int mi = 0; mi < 4; ++mi)
#pragma unroll
      for (int ni = 0; ni < 4; ++ni)
        acc[mi][ni] = __builtin_amdgcn_mfma_f32_16x16x32_bf16(a[mi], b[ni], acc[mi][ni], 0, 0, 0);
    __syncthreads();
  }

  const int crow = bm * 128 + wr * 64 + (lane >> 4) * 4;
  const int ccol = bn * 128 + wc * 64 + row15;
#pragma unroll
  for (int mi = 0; mi < 4; ++mi)
#pragma unroll
    for (int ni = 0; ni < 4; ++ni) {
      const int col = ccol + ni * 16;
      const float bv = bias[col];
#pragma unroll
      for (int r = 0; r < 4; ++r) {
        const int row = crow + mi * 16 + r;
        float v = acc[mi][ni][r] + bv;
        if (out_bf16)
          reinterpret_cast<bf16*>(Cout)[(size_t)row * N + col] = __float2bfloat16(v);
        else
          reinterpret_cast<float*>(Cout)[(size_t)row * N + col] = v;
      }
    }
}

// ---------------- RoPE in-place on qkv [s][3456] ----------------
__global__ __launch_bounds__(256) void rope_inplace(bf16* __restrict__ qkv,
                                                    const float* __restrict__ ang) {
  const int s = blockIdx.x;
  bf16* row = qkv + (size_t)s * QKVN;
  for (int i = threadIdx.x; i < 2 * NH * 36; i += 256) {
    int t   = i / (NH * 36);
    int rem = i - t * (NH * 36);
    int h   = rem / 36;
    int d2  = rem - h * 36;
    float a  = ang[s * 36 + d2];
    float cs = cosf(a), sn = sinf(a);
    bf16* p = row + t * ED + h * HD + d2;
    float x1 = __bfloat162float(p[0]);
    float x2 = __bfloat162float(p[36]);
    p[0]  = __float2bfloat16(x1 * cs - x2 * sn);
    p[36] = __float2bfloat16(x2 * cs + x1 * sn);
  }
}

// ---------------- flash attention v14 ----------------
// R14 base + K staged in LDS once per block (async gload_lds, chunk-linear ->
// row-major Ks[64][72]) -> cuts K L1 cache-line traffic 5.3x (the 12 strided
// global K loads x 4 waves were ~12k lines/CU/tile of L1 serialization).
// Schedule (single Ks + single Vt, 2 barriers):
//   BAR_A (staging kt drained) | qkt(kt) reads Ks; pv(kt) reads own Ps + Vt
//   BAR_B (all reads done)     | stage_k(kt+1) async + stage_v(kt+1) reg-rotation
__global__ __launch_bounds__(256, 4) void attn(const bf16* __restrict__ qkv,
                                               bf16* __restrict__ ctx) {
  const int blk  = blockIdx.x;
  // swizzle: all 16 q-tiles of one (seg,head) land on one XCD for K/V L2 locality
  const int qt   = (blk >> 3) & 15;
  const int g    = (((blk >> 7) & 15) << 3) | (blk & 7);
  const int head = g & 15;
  const int seg  = g >> 4;
  const int q0   = seg * SEGLEN + qt * 128;

  const int tid = threadIdx.x, lane = tid & 63, w = tid >> 6;
  const int row15 = lane & 15, hi = lane >> 4, koff = hi << 3;

  __shared__ __align__(16) bf16 Ks[64 * 72];   // row-major, staged via gload_lds (chunk-linear)
  __shared__ __align__(16) bf16 Vt[80 * 72];   // [d][kv] stride 72, chunk-rotated; row 72 = ones
  __shared__ __align__(16) bf16 Ps[128 * 72];  // per-wave exclusive rows

  const bf16* Qg = qkv + (size_t)q0 * QKVN + head * HD;
  const bf16* Kg = qkv + (size_t)(seg * SEGLEN) * QKVN + ED + head * HD;
  const bf16* Vg = qkv + (size_t)(seg * SEGLEN) * QKVN + 2 * ED + head * HD;

  // init pad rows 72..79 of Vt (row 72 = 1.0 row-sum column)
  {
    const bf16 one  = __float2bfloat16(1.0f);
    const bf16 zerob = __float2bfloat16(0.0f);
    for (int e = tid; e < 8 * 72; e += 256)
      Vt[72 * 72 + e] = (e < 72) ? one : zerob;
  }

  // Q fragments in registers (2 m-frags x 3 k-chunks; chunk 2 = cols 64..71, low lanes only)
  const bf16x8 zero8 = {};
  bf16x8 aq[2][3];
#pragma unroll
  for (int m = 0; m < 2; ++m) {
    const bf16* qrow = Qg + (size_t)(w * 32 + m * 16 + row15) * QKVN;
    aq[m][0] = *reinterpret_cast<const bf16x8*>(qrow + koff);
    aq[m][1] = *reinterpret_cast<const bf16x8*>(qrow + 32 + koff);
    aq[m][2] = (hi == 0) ? *reinterpret_cast<const bf16x8*>(qrow + 64) : zero8;
  }

  f32x4 oacc[2][5] = {};
  const float c2 = 0.11785113019775793f * 1.4426950408889634f;  // scale * log2(e)

  // async K staging: 576 16B-chunks (64 rows x 9 chunks), chunk-linear -> Ks[64][72]
  auto stage_k = [&](int kt2) {
    const bf16* Kt = Kg + (size_t)kt2 * 64 * QKVN;
    char* KsB = (char*)Ks;
    for (int gq = w; gq < 9; gq += 4) {
      int chunk = gq * 64 + lane;
      int row = chunk / 9;
      int cc  = chunk - row * 9;
      gload_lds16(Kt + (size_t)row * QKVN + cc * 8, KsB + gq * 1024);
    }
  };

  // V staging with transpose + column rotation jj=(j+8*(d>>3))&63 (reg path, verified)
  auto stage_v = [&](int kt2) {
    const bf16* src0 = Vg + (size_t)kt2 * 64 * QKVN;
    for (int c = tid; c < 576; c += 256) {
      int j = c / 9, m9 = c - j * 9;
      int d0 = m9 << 3;
      int jj = (j + (m9 << 3)) & 63;
      bf16x8 v = *reinterpret_cast<const bf16x8*>(src0 + (size_t)j * QKVN + d0);
      const unsigned short* u = reinterpret_cast<const unsigned short*>(&v);
#pragma unroll
      for (int e = 0; e < 8; ++e)
        Vt[(d0 + e) * 72 + jj] = __builtin_bit_cast(bf16, u[e]);
    }
  };

  // QK^T (K from LDS) + fixed-shift softmax + u16 P-stores (own rows)
  auto qkt_soft = [&]() {
    f32x4 s[2][4] = {};
    __builtin_amdgcn_s_setprio(1);
#pragma unroll
    for (int ks = 0; ks < 2; ++ks) {
#pragma unroll
      for (int n = 0; n < 4; ++n) {
        bf16x8 bk = *reinterpret_cast<const bf16x8*>(&Ks[(n * 16 + row15) * 72 + ks * 32 + koff]);
        s[0][n] = __builtin_amdgcn_mfma_f32_16x16x32_bf16(aq[0][ks], bk, s[0][n], 0, 0, 0);
        s[1][n] = __builtin_amdgcn_mfma_f32_16x16x32_bf16(aq[1][ks], bk, s[1][n], 0, 0, 0);
      }
    }
#pragma unroll
    for (int n = 0; n < 4; ++n) {
      bf16x8 bk = (hi == 0) ? *reinterpret_cast<const bf16x8*>(&Ks[(n * 16 + row15) * 72 + 64]) : zero8;
      s[0][n] = __builtin_amdgcn_mfma_f32_16x16x32_bf16(aq[0][2], bk, s[0][n], 0, 0, 0);
      s[1][n] = __builtin_amdgcn_mfma_f32_16x16x32_bf16(aq[1][2], bk, s[1][n], 0, 0, 0);
    }
    __builtin_amdgcn_s_setprio(0);
    const int prow_base = w * 32 + hi * 4;
#pragma unroll
    for (int m = 0; m < 2; ++m)
#pragma unroll
      for (int n = 0; n < 4; ++n)
#pragma unroll
        for (int r = 0; r < 4; ++r) {
          float p = fexp2(fmaf(s[m][n][r], c2, -4.0f));
          Ps[(prow_base + m * 16 + r) * 72 + n * 16 + row15] =
              __builtin_bit_cast(bf16, f2bfbits(p));
        }
  };

  auto pv = [&]() {
    __builtin_amdgcn_s_setprio(1);
#pragma unroll
    for (int ks = 0; ks < 2; ++ks) {
      bf16x8 ap0 = *reinterpret_cast<const bf16x8*>(&Ps[(w * 32 + row15) * 72 + ks * 32 + koff]);
      bf16x8 ap1 = *reinterpret_cast<const bf16x8*>(&Ps[(w * 32 + 16 + row15) * 72 + ks * 32 + koff]);
#pragma unroll
      for (int n = 0; n < 5; ++n) {
        const int vrow = n * 16 + row15;
        const int col = (ks * 32 + (hi << 3) + ((vrow >> 3) << 3)) & 63;
        bf16x8 bv = *reinterpret_cast<const bf16x8*>(&Vt[vrow * 72 + col]);
        oacc[0][n] = __builtin_amdgcn_mfma_f32_16x16x32_bf16(ap0, bv, oacc[0][n], 0, 0, 0);
        oacc[1][n] = __builtin_amdgcn_mfma_f32_16x16x32_bf16(ap1, bv, oacc[1][n], 0, 0, 0);
      }
    }
    __builtin_amdgcn_s_setprio(0);
  };

  // prologue + main loop (2 barriers/tile, single Ks + single Vt)
  stage_k(0);
  stage_v(0);
  for (int kt = 0; kt < NT; ++kt) {
    __syncthreads();   // BAR_A: staging(kt) drained (vmcnt+lgkmcnt at barrier)
    qkt_soft();        // reads Ks, writes own Ps rows
    pv();              // reads own Ps rows + Vt
    __syncthreads();   // BAR_B: all waves done reading Ks/Vt of kt
    if (kt + 1 < NT) {
      stage_k(kt + 1);
      stage_v(kt + 1);
    }
  }

  // ---- epilogue: l = oacc[m][4] at row15==8; normalize & store ----
#pragma unroll
  for (int m = 0; m < 2; ++m) {
#pragma unroll
    for (int r = 0; r < 4; ++r) {
      float l = __shfl(oacc[m][4][r], (lane & 48) + 8);
      float inv = 1.0f / l;
#pragma unroll
      for (int n = 0; n < 5; ++n) {
        const int d = n * 16 + row15;
        if (d < HD) {
          const int row = q0 + w * 32 + m * 16 + hi * 4 + r;
          ctx[(size_t)row * ED + head * HD + d] = __float2bfloat16(oacc[m][n][r] * inv);
        }
      }
    }
  }
}

// ---------------- launch ----------------
extern "C" void kernel_launch(void* const* d_in, const int* in_sizes, int n_in,
                              void* d_out, int out_size, void* d_ws, size_t ws_size,
                              hipStream_t stream) {
  const float* hidden = (const float*)d_in[0];
  const float* qkv_w  = (const float*)d_in[1];
  const float* qkv_b  = (const float*)d_in[2];
  const float* out_w  = (const float*)d_in[3];
  const float* out_b  = (const float*)d_in[4];
  const float* rope   = (const float*)d_in[5];

  const size_t SZ_QKV = (size_t)SEQ * QKVN * 2;
  const size_t SZ_X   = (size_t)SEQ * ED * 2;
  const size_t SZ_W   = (size_t)QKVN * ED * 2;
  const size_t NEED   = SZ_QKV + SZ_X + SZ_W;
  if (ws_size < NEED) return;

  char* ws = (char*)d_ws;
  bf16* qkvbf = (bf16*)(ws);
  bf16* Xbf   = (bf16*)(ws + SZ_QKV);
  bf16* Wbf   = (bf16*)(ws + SZ_QKV + SZ_X);

  cvt_f32_bf16<<<(SEQ * ED / 4 + 255) / 256, 256, 0, stream>>>(hidden, Xbf, SEQ * ED / 4);
  cvt_f32_bf16<<<(QKVN * ED / 4 + 255) / 256, 256, 0, stream>>>(qkv_w, Wbf, QKVN * ED / 4);

  gemm_bt<<<(SEQ / 128) * (QKVN / 128), 256, 0, stream>>>(Xbf, Wbf, qkv_b, qkvbf,
                                                          SEQ, QKVN, ED, 1);

  cvt_f32_bf16<<<(ED * ED / 4 + 255) / 256, 256, 0, stream>>>(out_w, Wbf, ED * ED / 4);

  rope_inplace<<<SEQ, 256, 0, stream>>>(qkvbf, rope);

  attn<<<NSEG * NH * (SEGLEN / 128), 256, 0, stream>>>(qkvbf, Xbf);

  gemm_bt<<<(SEQ / 128) * (ED / 128), 256, 0, stream>>>(Xbf, Wbf, out_b, d_out,
                                                        SEQ, ED, ED, 0);
}

// Round 18
// 558.250 us; speedup vs baseline: 1.6942x; 1.0330x over previous
//
#include <hip/hip_runtime.h>
#include <hip/hip_bf16.h>
#include <cstdint>

#define SEQ   16384
#define ED    1152
#define NH    16
#define HD    72
#define NSEG  8
#define SEGLEN 2048
#define QKVN  3456
#define NT    (SEGLEN / 64)
#define VTROWS 80

typedef __bf16 bf16x8 __attribute__((ext_vector_type(8)));
typedef float  f32x4  __attribute__((ext_vector_type(4)));
typedef __hip_bfloat16 bf16;

__device__ __forceinline__ unsigned short f2bfbits(float f) {
  bf16 h = __float2bfloat16(f);
  return __builtin_bit_cast(unsigned short, h);
}

__device__ __forceinline__ float fexp2(float x) {
#if __has_builtin(__builtin_amdgcn_exp2f)
  return __builtin_amdgcn_exp2f(x);
#else
  return exp2f(x);
#endif
}

__device__ __forceinline__ void gload_lds16(const void* g, void* l) {
  __builtin_amdgcn_global_load_lds(
      (__attribute__((address_space(1))) void*)(void*)g,
      (__attribute__((address_space(3))) void*)l, 16, 0, 0);
}

// ---------------- prep kernels ----------------
__global__ __launch_bounds__(256) void cvt_f32_bf16(const float* __restrict__ in,
                                                    bf16* __restrict__ out, int n4) {
  int i = blockIdx.x * 256 + threadIdx.x;
  if (i >= n4) return;
  float4 v = reinterpret_cast<const float4*>(in)[i];
  ushort4 o;
  o.x = f2bfbits(v.x); o.y = f2bfbits(v.y); o.z = f2bfbits(v.z); o.w = f2bfbits(v.w);
  reinterpret_cast<ushort4*>(out)[i] = o;
}

// ---------------- GEMM: C[M][N] = A[M][K] * B[N][K]^T + bias, m97-style + XCD swizzle ----
__global__ __launch_bounds__(256) void gemm_bt(const bf16* __restrict__ A,
                                               const bf16* __restrict__ B,
                                               const float* __restrict__ bias,
                                               void* __restrict__ Cout,
                                               int M, int N, int K, int out_bf16) {
  __shared__ __align__(16) bf16 As[128 * 32];
  __shared__ __align__(16) bf16 Bs[128 * 32];
  const int nt   = N >> 7;
  const int nwg  = gridDim.x;
  const int cpx  = nwg >> 3;
  const int bid  = blockIdx.x;
  const int swz  = (bid & 7) * cpx + (bid >> 3);
  const int bm   = swz / nt;
  const int bn   = swz % nt;
  const int tid  = threadIdx.x;
  const int lane = tid & 63;
  const int wave = tid >> 6;
  const int wr   = wave >> 1, wc = wave & 1;

  const bf16* Ab = A + (size_t)(bm * 128) * K;
  const bf16* Bb = B + (size_t)(bn * 128) * K;
  const int r0 = tid >> 2;
  const int c0 = (tid & 3) << 3;

  char* AsB = (char*)As;
  char* BsB = (char*)Bs;
  const int ldsoff = wave * 1024;

  const int row15 = lane & 15;
  const int koff  = (lane >> 4) << 3;

  f32x4 acc[4][4] = {};

  for (int k0 = 0; k0 < K; k0 += 32) {
    gload_lds16(Ab + (size_t)r0 * K + k0 + c0,        AsB + ldsoff);
    gload_lds16(Ab + (size_t)(r0 + 64) * K + k0 + c0, AsB + 4096 + ldsoff);
    gload_lds16(Bb + (size_t)r0 * K + k0 + c0,        BsB + ldsoff);
    gload_lds16(Bb + (size_t)(r0 + 64) * K + k0 + c0, BsB + 4096 + ldsoff);
    __syncthreads();
    bf16x8 a[4], b[4];
#pragma unroll
    for (int mi = 0; mi < 4; ++mi)
      a[mi] = *reinterpret_cast<const bf16x8*>(&As[(wr * 64 + mi * 16 + row15) * 32 + koff]);
#pragma unroll
    for (int ni = 0; ni < 4; ++ni)
      b[ni] = *reinterpret_cast<const bf16x8*>(&Bs[(wc * 64 + ni * 16 + row15) * 32 + koff]);
#pragma unroll
    for (int mi = 0; mi < 4; ++mi)
#pragma unroll
      for (int ni = 0; ni < 4; ++ni)
        acc[mi][ni] = __builtin_amdgcn_mfma_f32_16x16x32_bf16(a[mi], b[ni], acc[mi][ni], 0, 0, 0);
    __syncthreads();
  }

  const int crow = bm * 128 + wr * 64 + (lane >> 4) * 4;
  const int ccol = bn * 128 + wc * 64 + row15;
#pragma unroll
  for (int mi = 0; mi < 4; ++mi)
#pragma unroll
    for (int ni = 0; ni < 4; ++ni) {
      const int col = ccol + ni * 16;
      const float bv = bias[col];
#pragma unroll
      for (int r = 0; r < 4; ++r) {
        const int row = crow + mi * 16 + r;
        float v = acc[mi][ni][r] + bv;
        if (out_bf16)
          reinterpret_cast<bf16*>(Cout)[(size_t)row * N + col] = __float2bfloat16(v);
        else
          reinterpret_cast<float*>(Cout)[(size_t)row * N + col] = v;
      }
    }
}

// ---------------- RoPE in-place on qkv [s][3456] ----------------
__global__ __launch_bounds__(256) void rope_inplace(bf16* __restrict__ qkv,
                                                    const float* __restrict__ ang) {
  const int s = blockIdx.x;
  bf16* row = qkv + (size_t)s * QKVN;
  for (int i = threadIdx.x; i < 2 * NH * 36; i += 256) {
    int t   = i / (NH * 36);
    int rem = i - t * (NH * 36);
    int h   = rem / 36;
    int d2  = rem - h * 36;
    float a  = ang[s * 36 + d2];
    float cs = cosf(a), sn = sinf(a);
    bf16* p = row + t * ED + h * HD + d2;
    float x1 = __bfloat162float(p[0]);
    float x2 = __bfloat162float(p[36]);
    p[0]  = __float2bfloat16(x1 * cs - x2 * sn);
    p[36] = __float2bfloat16(x2 * cs + x1 * sn);
  }
}

// ---------------- V transpose -> global V^T[h][d][s] with per-row bank rotation ----
// Within each 64-col block: logical 8-elem group jg of row d stored at group
// (jg + (d&7)) & 7. Row 72 = ones (row-sum column), 73..79 = 0.
// (R15-verified transpose core; only the write rotation differs.)
__global__ __launch_bounds__(256, 4) void transpose_v(const bf16* __restrict__ qkv,
                                                      bf16* __restrict__ vt) {
  const int h  = blockIdx.x & 15;
  const int st = blockIdx.x >> 4;
  const int s0 = st * 64;
  const int tid = threadIdx.x;
  __shared__ __align__(16) bf16 Lt[72 * 72];  // [d][s-rot], stride 72, rotated by (d>>3)

  const bf16* src = qkv + (size_t)s0 * QKVN + 2 * ED + h * HD;
  for (int c = tid; c < 576; c += 256) {
    int j = c / 9, m9 = c - j * 9;
    int d0 = m9 << 3;
    int jj = (j + (m9 << 3)) & 63;
    bf16x8 v = *reinterpret_cast<const bf16x8*>(src + (size_t)j * QKVN + d0);
    const unsigned short* u = reinterpret_cast<const unsigned short*>(&v);
#pragma unroll
    for (int e = 0; e < 8; ++e)
      Lt[(d0 + e) * 72 + jj] = __builtin_bit_cast(bf16, u[e]);
  }
  __syncthreads();

  bf16x8 ones8, zero8 = {};
  {
    unsigned short ob = f2bfbits(1.0f);
#pragma unroll
    for (int e = 0; e < 8; ++e) ones8[e] = __builtin_bit_cast(__bf16, ob);
  }
  bf16* dst = vt + (size_t)(h * VTROWS) * SEQ + s0;
  for (int c = tid; c < VTROWS * 8; c += 256) {
    int d = c >> 3, sc = c & 7;
    bf16x8 v;
    int og = sc;
    if (d < 72) {
      int col = (((sc + (d >> 3)) << 3)) & 63;   // undo the Lt stage rotation
      v = *reinterpret_cast<const bf16x8*>(&Lt[d * 72 + col]);
      og = (sc + (d & 7)) & 7;                   // bake per-row bank rotation
    } else {
      v = (d == 72) ? ones8 : zero8;
    }
    *reinterpret_cast<bf16x8*>(dst + (size_t)d * SEQ + (og << 3)) = v;
  }
}

// ---------------- flash attention v15 ----------------
// R17 base + V staged via pure global_load_lds from pre-rotated global V^T
// (zero transpose VALU / zero scalar LDS writes in the k-loop).
__global__ __launch_bounds__(256, 4) void attn(const bf16* __restrict__ qkv,
                                               const bf16* __restrict__ vt,
                                               bf16* __restrict__ ctx) {
  const int blk  = blockIdx.x;
  // swizzle: all 16 q-tiles of one (seg,head) land on one XCD for K/V L2 locality
  const int qt   = (blk >> 3) & 15;
  const int g    = (((blk >> 7) & 15) << 3) | (blk & 7);
  const int head = g & 15;
  const int seg  = g >> 4;
  const int q0   = seg * SEGLEN + qt * 128;

  const int tid = threadIdx.x, lane = tid & 63, w = tid >> 6;
  const int row15 = lane & 15, hi = lane >> 4, koff = hi << 3;

  __shared__ __align__(16) bf16 Ks[64 * 72];   // row-major, staged via gload_lds
  __shared__ __align__(16) bf16 Vt[VTROWS * 64];  // [d][kv-rot], staged via gload_lds
  __shared__ __align__(16) bf16 Ps[128 * 72];  // per-wave exclusive rows

  const bf16* Qg  = qkv + (size_t)q0 * QKVN + head * HD;
  const bf16* Kg  = qkv + (size_t)(seg * SEGLEN) * QKVN + ED + head * HD;
  const bf16* Vtg = vt + (size_t)(head * VTROWS) * SEQ + seg * SEGLEN;

  // Q fragments in registers (2 m-frags x 3 k-chunks; chunk 2 = cols 64..71, low lanes only)
  const bf16x8 zero8 = {};
  bf16x8 aq[2][3];
#pragma unroll
  for (int m = 0; m < 2; ++m) {
    const bf16* qrow = Qg + (size_t)(w * 32 + m * 16 + row15) * QKVN;
    aq[m][0] = *reinterpret_cast<const bf16x8*>(qrow + koff);
    aq[m][1] = *reinterpret_cast<const bf16x8*>(qrow + 32 + koff);
    aq[m][2] = (hi == 0) ? *reinterpret_cast<const bf16x8*>(qrow + 64) : zero8;
  }

  f32x4 oacc[2][5] = {};
  const float c2 = 0.11785113019775793f * 1.4426950408889634f;  // scale * log2(e)

  // async K staging: 576 16B-chunks (64 rows x 9 chunks), chunk-linear -> Ks[64][72]
  auto stage_k = [&](int kt2) {
    const bf16* Kt = Kg + (size_t)kt2 * 64 * QKVN;
    char* KsB = (char*)Ks;
    for (int gq = w; gq < 9; gq += 4) {
      int chunk = gq * 64 + lane;
      int row = chunk / 9;
      int cc  = chunk - row * 9;
      gload_lds16(Kt + (size_t)row * QKVN + cc * 8, KsB + gq * 1024);
    }
  };

  // async V^T staging: 640 16B-chunks (80 rows x 8 chunks) -> Vt[80][64] (pre-rotated)
  auto stage_v = [&](int kt2) {
    const bf16* Vsrc = Vtg + (size_t)kt2 * 64;
    char* VsB = (char*)Vt;
    for (int i = w; i < 10; i += 4) {
      int c = i * 64 + lane;
      int d = c >> 3, g8 = c & 7;
      gload_lds16(Vsrc + (size_t)d * SEQ + g8 * 8, VsB + i * 1024);
    }
  };

  // QK^T (K from LDS) + fixed-shift softmax + u16 P-stores (own rows)
  auto qkt_soft = [&]() {
    f32x4 s[2][4] = {};
    __builtin_amdgcn_s_setprio(1);
#pragma unroll
    for (int ks = 0; ks < 2; ++ks) {
#pragma unroll
      for (int n = 0; n < 4; ++n) {
        bf16x8 bk = *reinterpret_cast<const bf16x8*>(&Ks[(n * 16 + row15) * 72 + ks * 32 + koff]);
        s[0][n] = __builtin_amdgcn_mfma_f32_16x16x32_bf16(aq[0][ks], bk, s[0][n], 0, 0, 0);
        s[1][n] = __builtin_amdgcn_mfma_f32_16x16x32_bf16(aq[1][ks], bk, s[1][n], 0, 0, 0);
      }
    }
#pragma unroll
    for (int n = 0; n < 4; ++n) {
      bf16x8 bk = (hi == 0) ? *reinterpret_cast<const bf16x8*>(&Ks[(n * 16 + row15) * 72 + 64]) : zero8;
      s[0][n] = __builtin_amdgcn_mfma_f32_16x16x32_bf16(aq[0][2], bk, s[0][n], 0, 0, 0);
      s[1][n] = __builtin_amdgcn_mfma_f32_16x16x32_bf16(aq[1][2], bk, s[1][n], 0, 0, 0);
    }
    __builtin_amdgcn_s_setprio(0);
    const int prow_base = w * 32 + hi * 4;
#pragma unroll
    for (int m = 0; m < 2; ++m)
#pragma unroll
      for (int n = 0; n < 4; ++n)
#pragma unroll
        for (int r = 0; r < 4; ++r) {
          float p = fexp2(fmaf(s[m][n][r], c2, -4.0f));
          Ps[(prow_base + m * 16 + r) * 72 + n * 16 + row15] =
              __builtin_bit_cast(bf16, f2bfbits(p));
        }
  };

  auto pv = [&]() {
    __builtin_amdgcn_s_setprio(1);
#pragma unroll
    for (int ks = 0; ks < 2; ++ks) {
      bf16x8 ap0 = *reinterpret_cast<const bf16x8*>(&Ps[(w * 32 + row15) * 72 + ks * 32 + koff]);
      bf16x8 ap1 = *reinterpret_cast<const bf16x8*>(&Ps[(w * 32 + 16 + row15) * 72 + ks * 32 + koff]);
#pragma unroll
      for (int n = 0; n < 5; ++n) {
        const int vrow = n * 16 + row15;
        const int cA = ((((ks << 2) + hi + (vrow & 7)) & 7) << 3);  // pre-baked rotation
        bf16x8 bv = *reinterpret_cast<const bf16x8*>(&Vt[vrow * 64 + (ks == 0 ? cA : cA)]);
        // NOTE: rotation groups are mod-8 within the 64-col tile; ks is folded into
        // the group index (ks*4), so cA alone addresses the correct 16B span.
        oacc[0][n] = __builtin_amdgcn_mfma_f32_16x16x32_bf16(ap0, bv, oacc[0][n], 0, 0, 0);
        oacc[1][n] = __builtin_amdgcn_mfma_f32_16x16x32_bf16(ap1, bv, oacc[1][n], 0, 0, 0);
      }
    }
    __builtin_amdgcn_s_setprio(0);
  };

  // prologue + main loop (2 barriers/tile, single Ks + single Vt)
  stage_k(0);
  stage_v(0);
  for (int kt = 0; kt < NT; ++kt) {
    __syncthreads();   // BAR_A: staging(kt) drained
    qkt_soft();        // reads Ks, writes own Ps rows
    pv();              // reads own Ps rows + Vt
    __syncthreads();   // BAR_B: all waves done reading Ks/Vt of kt
    if (kt + 1 < NT) {
      stage_k(kt + 1);
      stage_v(kt + 1);
    }
  }

  // ---- epilogue: l = oacc[m][4] at row15==8; normalize & store ----
#pragma unroll
  for (int m = 0; m < 2; ++m) {
#pragma unroll
    for (int r = 0; r < 4; ++r) {
      float l = __shfl(oacc[m][4][r], (lane & 48) + 8);
      float inv = 1.0f / l;
#pragma unroll
      for (int n = 0; n < 5; ++n) {
        const int d = n * 16 + row15;
        if (d < HD) {
          const int row = q0 + w * 32 + m * 16 + hi * 4 + r;
          ctx[(size_t)row * ED + head * HD + d] = __float2bfloat16(oacc[m][n][r] * inv);
        }
      }
    }
  }
}

// ---------------- launch ----------------
extern "C" void kernel_launch(void* const* d_in, const int* in_sizes, int n_in,
                              void* d_out, int out_size, void* d_ws, size_t ws_size,
                              hipStream_t stream) {
  const float* hidden = (const float*)d_in[0];
  const float* qkv_w  = (const float*)d_in[1];
  const float* qkv_b  = (const float*)d_in[2];
  const float* out_w  = (const float*)d_in[3];
  const float* out_b  = (const float*)d_in[4];
  const float* rope   = (const float*)d_in[5];

  const size_t SZ_QKV = (size_t)SEQ * QKVN * 2;
  const size_t SZ_X   = (size_t)SEQ * ED * 2;
  const size_t SZ_W   = (size_t)QKVN * ED * 2;
  const size_t SZ_VT  = (size_t)NH * VTROWS * SEQ * 2;
  const size_t NEED   = SZ_QKV + SZ_X + SZ_W + SZ_VT;
  if (ws_size < NEED) return;

  char* ws = (char*)d_ws;
  bf16* qkvbf = (bf16*)(ws);
  bf16* Xbf   = (bf16*)(ws + SZ_QKV);
  bf16* Wbf   = (bf16*)(ws + SZ_QKV + SZ_X);
  bf16* vtb   = (bf16*)(ws + SZ_QKV + SZ_X + SZ_W);

  cvt_f32_bf16<<<(SEQ * ED / 4 + 255) / 256, 256, 0, stream>>>(hidden, Xbf, SEQ * ED / 4);
  cvt_f32_bf16<<<(QKVN * ED / 4 + 255) / 256, 256, 0, stream>>>(qkv_w, Wbf, QKVN * ED / 4);

  gemm_bt<<<(SEQ / 128) * (QKVN / 128), 256, 0, stream>>>(Xbf, Wbf, qkv_b, qkvbf,
                                                          SEQ, QKVN, ED, 1);

  cvt_f32_bf16<<<(ED * ED / 4 + 255) / 256, 256, 0, stream>>>(out_w, Wbf, ED * ED / 4);

  rope_inplace<<<SEQ, 256, 0, stream>>>(qkvbf, rope);

  transpose_v<<<NH * (SEQ / 64), 256, 0, stream>>>(qkvbf, vtb);

  attn<<<NSEG * NH * (SEGLEN / 128), 256, 0, stream>>>(qkvbf, vtb, Xbf);

  gemm_bt<<<(SEQ / 128) * (ED / 128), 256, 0, stream>>>(Xbf, Wbf, out_b, d_out,
                                                        SEQ, ED, ED, 0);
}

// Round 20
// 523.167 us; speedup vs baseline: 1.8078x; 1.0671x over previous
//
#include <hip/hip_runtime.h>
#include <hip/hip_bf16.h>
#include <cstdint>

#define SEQ   16384
#define ED    1152
#define NH    16
#define HD    72
#define NSEG  8
#define SEGLEN 2048
#define QKVN  3456
#define NT    (SEGLEN / 64)
#define VTROWS 80

typedef __bf16 bf16x8 __attribute__((ext_vector_type(8)));
typedef float  f32x4  __attribute__((ext_vector_type(4)));
typedef __hip_bfloat16 bf16;

__device__ __forceinline__ unsigned short f2bfbits(float f) {
  bf16 h = __float2bfloat16(f);
  return __builtin_bit_cast(unsigned short, h);
}

__device__ __forceinline__ float fexp2(float x) {
#if __has_builtin(__builtin_amdgcn_exp2f)
  return __builtin_amdgcn_exp2f(x);
#else
  return exp2f(x);
#endif
}

__device__ __forceinline__ void gload_lds16(const void* g, void* l) {
  __builtin_amdgcn_global_load_lds(
      (__attribute__((address_space(1))) void*)(void*)g,
      (__attribute__((address_space(3))) void*)l, 16, 0, 0);
}

// ---------------- prep kernels ----------------
__global__ __launch_bounds__(256) void cvt_f32_bf16(const float* __restrict__ in,
                                                    bf16* __restrict__ out, int n4) {
  int i = blockIdx.x * 256 + threadIdx.x;
  if (i >= n4) return;
  float4 v = reinterpret_cast<const float4*>(in)[i];
  ushort4 o;
  o.x = f2bfbits(v.x); o.y = f2bfbits(v.y); o.z = f2bfbits(v.z); o.w = f2bfbits(v.w);
  reinterpret_cast<ushort4*>(out)[i] = o;
}

// ---------------- GEMM: C[M][N] = A[M][K]*B[N][K]^T + bias ----------------
// m97 structure + XCD swizzle + BK=64 (the ONLY delta vs the verified R18 build):
// As/Bs are [2][128][32], each chunk identical to the verified BK=32 layout.
__global__ __launch_bounds__(256) void gemm_bt(const bf16* __restrict__ A,
                                               const bf16* __restrict__ B,
                                               const float* __restrict__ bias,
                                               void* __restrict__ Cout,
                                               int M, int N, int K, int out_bf16) {
  __shared__ __align__(16) bf16 As[2 * 128 * 32];
  __shared__ __align__(16) bf16 Bs[2 * 128 * 32];
  const int nt   = N >> 7;
  const int nwg  = gridDim.x;
  const int cpx  = nwg >> 3;
  const int bid  = blockIdx.x;
  const int swz  = (bid & 7) * cpx + (bid >> 3);
  const int bm   = swz / nt;
  const int bn   = swz % nt;
  const int tid  = threadIdx.x;
  const int lane = tid & 63;
  const int wave = tid >> 6;
  const int wr   = wave >> 1, wc = wave & 1;

  const bf16* Ab = A + (size_t)(bm * 128) * K;
  const bf16* Bb = B + (size_t)(bn * 128) * K;

  char* AsB = (char*)As;
  char* BsB = (char*)Bs;

  const int row15 = lane & 15;
  const int koff  = (lane >> 4) << 3;
  const int srow  = lane >> 2;          // 0..15 within 16-row stripe
  const int scol  = (lane & 3) << 3;    // 0,8,16,24

  f32x4 acc[4][4] = {};

  for (int k0 = 0; k0 < K; k0 += 64) {
    // staging: chunk i -> kk=i>>3, rows (i&7)*16 + lane/4, cols kk*32 + (lane&3)*8
#pragma unroll
    for (int i = wave; i < 16; i += 4) {
      const int kk = i >> 3, ib = i & 7;
      gload_lds16(Ab + (size_t)(ib * 16 + srow) * K + k0 + kk * 32 + scol, AsB + i * 1024);
      gload_lds16(Bb + (size_t)(ib * 16 + srow) * K + k0 + kk * 32 + scol, BsB + i * 1024);
    }
    __syncthreads();
#pragma unroll
    for (int kk = 0; kk < 2; ++kk) {
      bf16x8 a[4], b[4];
#pragma unroll
      for (int mi = 0; mi < 4; ++mi)
        a[mi] = *reinterpret_cast<const bf16x8*>(&As[kk * 4096 + (wr * 64 + mi * 16 + row15) * 32 + koff]);
#pragma unroll
      for (int ni = 0; ni < 4; ++ni)
        b[ni] = *reinterpret_cast<const bf16x8*>(&Bs[kk * 4096 + (wc * 64 + ni * 16 + row15) * 32 + koff]);
#pragma unroll
      for (int mi = 0; mi < 4; ++mi)
#pragma unroll
        for (int ni = 0; ni < 4; ++ni)
          acc[mi][ni] = __builtin_amdgcn_mfma_f32_16x16x32_bf16(a[mi], b[ni], acc[mi][ni], 0, 0, 0);
    }
    __syncthreads();
  }

  const int crow = bm * 128 + wr * 64 + (lane >> 4) * 4;
  const int ccol = bn * 128 + wc * 64 + row15;
#pragma unroll
  for (int mi = 0; mi < 4; ++mi)
#pragma unroll
    for (int ni = 0; ni < 4; ++ni) {
      const int col = ccol + ni * 16;
      const float bv = bias[col];
#pragma unroll
      for (int r = 0; r < 4; ++r) {
        const int row = crow + mi * 16 + r;
        float v = acc[mi][ni][r] + bv;
        if (out_bf16)
          reinterpret_cast<bf16*>(Cout)[(size_t)row * N + col] = __float2bfloat16(v);
        else
          reinterpret_cast<float*>(Cout)[(size_t)row * N + col] = v;
      }
    }
}

// ---------------- RoPE in-place on qkv [s][3456] ----------------
__global__ __launch_bounds__(256) void rope_inplace(bf16* __restrict__ qkv,
                                                    const float* __restrict__ ang) {
  const int s = blockIdx.x;
  bf16* row = qkv + (size_t)s * QKVN;
  for (int i = threadIdx.x; i < 2 * NH * 36; i += 256) {
    int t   = i / (NH * 36);
    int rem = i - t * (NH * 36);
    int h   = rem / 36;
    int d2  = rem - h * 36;
    float a  = ang[s * 36 + d2];
    float cs = cosf(a), sn = sinf(a);
    bf16* p = row + t * ED + h * HD + d2;
    float x1 = __bfloat162float(p[0]);
    float x2 = __bfloat162float(p[36]);
    p[0]  = __float2bfloat16(x1 * cs - x2 * sn);
    p[36] = __float2bfloat16(x2 * cs + x1 * sn);
  }
}

// ---------------- V transpose -> global V^T[h][d][s] with per-row bank rotation ----
__global__ __launch_bounds__(256, 4) void transpose_v(const bf16* __restrict__ qkv,
                                                      bf16* __restrict__ vt) {
  const int h  = blockIdx.x & 15;
  const int st = blockIdx.x >> 4;
  const int s0 = st * 64;
  const int tid = threadIdx.x;
  __shared__ __align__(16) bf16 Lt[72 * 72];

  const bf16* src = qkv + (size_t)s0 * QKVN + 2 * ED + h * HD;
  for (int c = tid; c < 576; c += 256) {
    int j = c / 9, m9 = c - j * 9;
    int d0 = m9 << 3;
    int jj = (j + (m9 << 3)) & 63;
    bf16x8 v = *reinterpret_cast<const bf16x8*>(src + (size_t)j * QKVN + d0);
    const unsigned short* u = reinterpret_cast<const unsigned short*>(&v);
#pragma unroll
    for (int e = 0; e < 8; ++e)
      Lt[(d0 + e) * 72 + jj] = __builtin_bit_cast(bf16, u[e]);
  }
  __syncthreads();

  bf16x8 ones8, zero8 = {};
  {
    unsigned short ob = f2bfbits(1.0f);
#pragma unroll
    for (int e = 0; e < 8; ++e) ones8[e] = __builtin_bit_cast(__bf16, ob);
  }
  bf16* dst = vt + (size_t)(h * VTROWS) * SEQ + s0;
  for (int c = tid; c < VTROWS * 8; c += 256) {
    int d = c >> 3, sc = c & 7;
    bf16x8 v;
    int og = sc;
    if (d < 72) {
      int col = (((sc + (d >> 3)) << 3)) & 63;
      v = *reinterpret_cast<const bf16x8*>(&Lt[d * 72 + col]);
      og = (sc + (d & 7)) & 7;
    } else {
      v = (d == 72) ? ones8 : zero8;
    }
    *reinterpret_cast<bf16x8*>(dst + (size_t)d * SEQ + (og << 3)) = v;
  }
}

// ---------------- flash attention v15 (EXACT R18 kernel, 229us verified) ----------------
__global__ __launch_bounds__(256, 4) void attn(const bf16* __restrict__ qkv,
                                               const bf16* __restrict__ vt,
                                               bf16* __restrict__ ctx) {
  const int blk  = blockIdx.x;
  const int qt   = (blk >> 3) & 15;
  const int g    = (((blk >> 7) & 15) << 3) | (blk & 7);
  const int head = g & 15;
  const int seg  = g >> 4;
  const int q0   = seg * SEGLEN + qt * 128;

  const int tid = threadIdx.x, lane = tid & 63, w = tid >> 6;
  const int row15 = lane & 15, hi = lane >> 4, koff = hi << 3;

  __shared__ __align__(16) bf16 Ks[64 * 72];
  __shared__ __align__(16) bf16 Vt[VTROWS * 64];
  __shared__ __align__(16) bf16 Ps[128 * 72];

  const bf16* Qg  = qkv + (size_t)q0 * QKVN + head * HD;
  const bf16* Kg  = qkv + (size_t)(seg * SEGLEN) * QKVN + ED + head * HD;
  const bf16* Vtg = vt + (size_t)(head * VTROWS) * SEQ + seg * SEGLEN;

  const bf16x8 zero8 = {};
  bf16x8 aq[2][3];
#pragma unroll
  for (int m = 0; m < 2; ++m) {
    const bf16* qrow = Qg + (size_t)(w * 32 + m * 16 + row15) * QKVN;
    aq[m][0] = *reinterpret_cast<const bf16x8*>(qrow + koff);
    aq[m][1] = *reinterpret_cast<const bf16x8*>(qrow + 32 + koff);
    aq[m][2] = (hi == 0) ? *reinterpret_cast<const bf16x8*>(qrow + 64) : zero8;
  }

  f32x4 oacc[2][5] = {};
  const float c2 = 0.11785113019775793f * 1.4426950408889634f;  // scale * log2(e)

  auto stage_k = [&](int kt2) {
    const bf16* Kt = Kg + (size_t)kt2 * 64 * QKVN;
    char* KsB = (char*)Ks;
    for (int gq = w; gq < 9; gq += 4) {
      int chunk = gq * 64 + lane;
      int row = chunk / 9;
      int cc  = chunk - row * 9;
      gload_lds16(Kt + (size_t)row * QKVN + cc * 8, KsB + gq * 1024);
    }
  };

  auto stage_v = [&](int kt2) {
    const bf16* Vsrc = Vtg + (size_t)kt2 * 64;
    char* VsB = (char*)Vt;
    for (int i = w; i < 10; i += 4) {
      int c = i * 64 + lane;
      int d = c >> 3, g8 = c & 7;
      gload_lds16(Vsrc + (size_t)d * SEQ + g8 * 8, VsB + i * 1024);
    }
  };

  auto qkt_soft = [&]() {
    f32x4 s[2][4] = {};
    __builtin_amdgcn_s_setprio(1);
#pragma unroll
    for (int ks = 0; ks < 2; ++ks) {
#pragma unroll
      for (int n = 0; n < 4; ++n) {
        bf16x8 bk = *reinterpret_cast<const bf16x8*>(&Ks[(n * 16 + row15) * 72 + ks * 32 + koff]);
        s[0][n] = __builtin_amdgcn_mfma_f32_16x16x32_bf16(aq[0][ks], bk, s[0][n], 0, 0, 0);
        s[1][n] = __builtin_amdgcn_mfma_f32_16x16x32_bf16(aq[1][ks], bk, s[1][n], 0, 0, 0);
      }
    }
#pragma unroll
    for (int n = 0; n < 4; ++n) {
      bf16x8 bk = (hi == 0) ? *reinterpret_cast<const bf16x8*>(&Ks[(n * 16 + row15) * 72 + 64]) : zero8;
      s[0][n] = __builtin_amdgcn_mfma_f32_16x16x32_bf16(aq[0][2], bk, s[0][n], 0, 0, 0);
      s[1][n] = __builtin_amdgcn_mfma_f32_16x16x32_bf16(aq[1][2], bk, s[1][n], 0, 0, 0);
    }
    __builtin_amdgcn_s_setprio(0);
    const int prow_base = w * 32 + hi * 4;
#pragma unroll
    for (int m = 0; m < 2; ++m)
#pragma unroll
      for (int n = 0; n < 4; ++n)
#pragma unroll
        for (int r = 0; r < 4; ++r) {
          float p = fexp2(fmaf(s[m][n][r], c2, -4.0f));
          Ps[(prow_base + m * 16 + r) * 72 + n * 16 + row15] =
              __builtin_bit_cast(bf16, f2bfbits(p));
        }
  };

  auto pv = [&]() {
    __builtin_amdgcn_s_setprio(1);
#pragma unroll
    for (int ks = 0; ks < 2; ++ks) {
      bf16x8 ap0 = *reinterpret_cast<const bf16x8*>(&Ps[(w * 32 + row15) * 72 + ks * 32 + koff]);
      bf16x8 ap1 = *reinterpret_cast<const bf16x8*>(&Ps[(w * 32 + 16 + row15) * 72 + ks * 32 + koff]);
#pragma unroll
      for (int n = 0; n < 5; ++n) {
        const int vrow = n * 16 + row15;
        const int cA = ((((ks << 2) + hi + (vrow & 7)) & 7) << 3);  // pre-baked rotation
        bf16x8 bv = *reinterpret_cast<const bf16x8*>(&Vt[vrow * 64 + cA]);
        oacc[0][n] = __builtin_amdgcn_mfma_f32_16x16x32_bf16(ap0, bv, oacc[0][n], 0, 0, 0);
        oacc[1][n] = __builtin_amdgcn_mfma_f32_16x16x32_bf16(ap1, bv, oacc[1][n], 0, 0, 0);
      }
    }
    __builtin_amdgcn_s_setprio(0);
  };

  stage_k(0);
  stage_v(0);
  for (int kt = 0; kt < NT; ++kt) {
    __syncthreads();   // BAR_A: staging(kt) drained
    qkt_soft();
    pv();
    __syncthreads();   // BAR_B: all waves done reading Ks/Vt of kt
    if (kt + 1 < NT) {
      stage_k(kt + 1);
      stage_v(kt + 1);
    }
  }

#pragma unroll
  for (int m = 0; m < 2; ++m) {
#pragma unroll
    for (int r = 0; r < 4; ++r) {
      float l = __shfl(oacc[m][4][r], (lane & 48) + 8);
      float inv = 1.0f / l;
#pragma unroll
      for (int n = 0; n < 5; ++n) {
        const int d = n * 16 + row15;
        if (d < HD) {
          const int row = q0 + w * 32 + m * 16 + hi * 4 + r;
          ctx[(size_t)row * ED + head * HD + d] = __float2bfloat16(oacc[m][n][r] * inv);
        }
      }
    }
  }
}

// ---------------- launch ----------------
extern "C" void kernel_launch(void* const* d_in, const int* in_sizes, int n_in,
                              void* d_out, int out_size, void* d_ws, size_t ws_size,
                              hipStream_t stream) {
  const float* hidden = (const float*)d_in[0];
  const float* qkv_w  = (const float*)d_in[1];
  const float* qkv_b  = (const float*)d_in[2];
  const float* out_w  = (const float*)d_in[3];
  const float* out_b  = (const float*)d_in[4];
  const float* rope   = (const float*)d_in[5];

  const size_t SZ_QKV = (size_t)SEQ * QKVN * 2;
  const size_t SZ_X   = (size_t)SEQ * ED * 2;
  const size_t SZ_W   = (size_t)QKVN * ED * 2;
  const size_t SZ_VT  = (size_t)NH * VTROWS * SEQ * 2;
  const size_t NEED   = SZ_QKV + SZ_X + SZ_W + SZ_VT;
  if (ws_size < NEED) return;

  char* ws = (char*)d_ws;
  bf16* qkvbf = (bf16*)(ws);
  bf16* Xbf   = (bf16*)(ws + SZ_QKV);
  bf16* Wbf   = (bf16*)(ws + SZ_QKV + SZ_X);
  bf16* vtb   = (bf16*)(ws + SZ_QKV + SZ_X + SZ_W);

  cvt_f32_bf16<<<(SEQ * ED / 4 + 255) / 256, 256, 0, stream>>>(hidden, Xbf, SEQ * ED / 4);
  cvt_f32_bf16<<<(QKVN * ED / 4 + 255) / 256, 256, 0, stream>>>(qkv_w, Wbf, QKVN * ED / 4);

  gemm_bt<<<(SEQ / 128) * (QKVN / 128), 256, 0, stream>>>(Xbf, Wbf, qkv_b, qkvbf,
                                                          SEQ, QKVN, ED, 1);

  cvt_f32_bf16<<<(ED * ED / 4 + 255) / 256, 256, 0, stream>>>(out_w, Wbf, ED * ED / 4);

  rope_inplace<<<SEQ, 256, 0, stream>>>(qkvbf, rope);

  transpose_v<<<NH * (SEQ / 64), 256, 0, stream>>>(qkvbf, vtb);

  attn<<<NSEG * NH * (SEGLEN / 128), 256, 0, stream>>>(qkvbf, vtb, Xbf);

  gemm_bt<<<(SEQ / 128) * (ED / 128), 256, 0, stream>>>(Xbf, Wbf, out_b, d_out,
                                                        SEQ, ED, ED, 0);
}

// Round 22
// 519.797 us; speedup vs baseline: 1.8195x; 1.0065x over previous
//
#include <hip/hip_runtime.h>
#include <hip/hip_bf16.h>
#include <cstdint>

#define SEQ   16384
#define ED    1152
#define NH    16
#define HD    72
#define NSEG  8
#define SEGLEN 2048
#define QKVN  3456
#define NT    (SEGLEN / 64)
#define VTROWS 80

typedef __bf16 bf16x8 __attribute__((ext_vector_type(8)));
typedef float  f32x4  __attribute__((ext_vector_type(4)));
typedef __hip_bfloat16 bf16;

__device__ __forceinline__ unsigned short f2bfbits(float f) {
  bf16 h = __float2bfloat16(f);
  return __builtin_bit_cast(unsigned short, h);
}

__device__ __forceinline__ float fexp2(float x) {
#if __has_builtin(__builtin_amdgcn_exp2f)
  return __builtin_amdgcn_exp2f(x);
#else
  return exp2f(x);
#endif
}

// round-half-up f32->bf16 (2 VALU); valid for finite positive p (never NaN here)
__device__ __forceinline__ unsigned short f2bf_rhu(float f) {
  unsigned int b = __builtin_bit_cast(unsigned int, f);
  return (unsigned short)((b + 0x8000u) >> 16);
}

__device__ __forceinline__ void gload_lds16(const void* g, void* l) {
  __builtin_amdgcn_global_load_lds(
      (__attribute__((address_space(1))) void*)(void*)g,
      (__attribute__((address_space(3))) void*)l, 16, 0, 0);
}

// ---------------- prep kernels ----------------
__global__ __launch_bounds__(256) void cvt_f32_bf16(const float* __restrict__ in,
                                                    bf16* __restrict__ out, int n4) {
  int i = blockIdx.x * 256 + threadIdx.x;
  if (i >= n4) return;
  float4 v = reinterpret_cast<const float4*>(in)[i];
  ushort4 o;
  o.x = f2bfbits(v.x); o.y = f2bfbits(v.y); o.z = f2bfbits(v.z); o.w = f2bfbits(v.w);
  reinterpret_cast<ushort4*>(out)[i] = o;
}

// ---------------- GEMM: C[M][N] = A[M][K]*B[N][K]^T + bias (BK=64, R20-verified) ----
__global__ __launch_bounds__(256) void gemm_bt(const bf16* __restrict__ A,
                                               const bf16* __restrict__ B,
                                               const float* __restrict__ bias,
                                               void* __restrict__ Cout,
                                               int M, int N, int K, int out_bf16) {
  __shared__ __align__(16) bf16 As[2 * 128 * 32];
  __shared__ __align__(16) bf16 Bs[2 * 128 * 32];
  const int nt   = N >> 7;
  const int nwg  = gridDim.x;
  const int cpx  = nwg >> 3;
  const int bid  = blockIdx.x;
  const int swz  = (bid & 7) * cpx + (bid >> 3);
  const int bm   = swz / nt;
  const int bn   = swz % nt;
  const int tid  = threadIdx.x;
  const int lane = tid & 63;
  const int wave = tid >> 6;
  const int wr   = wave >> 1, wc = wave & 1;

  const bf16* Ab = A + (size_t)(bm * 128) * K;
  const bf16* Bb = B + (size_t)(bn * 128) * K;

  char* AsB = (char*)As;
  char* BsB = (char*)Bs;

  const int row15 = lane & 15;
  const int koff  = (lane >> 4) << 3;
  const int srow  = lane >> 2;
  const int scol  = (lane & 3) << 3;

  f32x4 acc[4][4] = {};

  for (int k0 = 0; k0 < K; k0 += 64) {
#pragma unroll
    for (int i = wave; i < 16; i += 4) {
      const int kk = i >> 3, ib = i & 7;
      gload_lds16(Ab + (size_t)(ib * 16 + srow) * K + k0 + kk * 32 + scol, AsB + i * 1024);
      gload_lds16(Bb + (size_t)(ib * 16 + srow) * K + k0 + kk * 32 + scol, BsB + i * 1024);
    }
    __syncthreads();
#pragma unroll
    for (int kk = 0; kk < 2; ++kk) {
      bf16x8 a[4], b[4];
#pragma unroll
      for (int mi = 0; mi < 4; ++mi)
        a[mi] = *reinterpret_cast<const bf16x8*>(&As[kk * 4096 + (wr * 64 + mi * 16 + row15) * 32 + koff]);
#pragma unroll
      for (int ni = 0; ni < 4; ++ni)
        b[ni] = *reinterpret_cast<const bf16x8*>(&Bs[kk * 4096 + (wc * 64 + ni * 16 + row15) * 32 + koff]);
#pragma unroll
      for (int mi = 0; mi < 4; ++mi)
#pragma unroll
        for (int ni = 0; ni < 4; ++ni)
          acc[mi][ni] = __builtin_amdgcn_mfma_f32_16x16x32_bf16(a[mi], b[ni], acc[mi][ni], 0, 0, 0);
    }
    __syncthreads();
  }

  const int crow = bm * 128 + wr * 64 + (lane >> 4) * 4;
  const int ccol = bn * 128 + wc * 64 + row15;
#pragma unroll
  for (int mi = 0; mi < 4; ++mi)
#pragma unroll
    for (int ni = 0; ni < 4; ++ni) {
      const int col = ccol + ni * 16;
      const float bv = bias[col];
#pragma unroll
      for (int r = 0; r < 4; ++r) {
        const int row = crow + mi * 16 + r;
        float v = acc[mi][ni][r] + bv;
        if (out_bf16)
          reinterpret_cast<bf16*>(Cout)[(size_t)row * N + col] = __float2bfloat16(v);
        else
          reinterpret_cast<float*>(Cout)[(size_t)row * N + col] = v;
      }
    }
}

// ---------------- RoPE in-place on qkv [s][3456] ----------------
__global__ __launch_bounds__(256) void rope_inplace(bf16* __restrict__ qkv,
                                                    const float* __restrict__ ang) {
  const int s = blockIdx.x;
  bf16* row = qkv + (size_t)s * QKVN;
  for (int i = threadIdx.x; i < 2 * NH * 36; i += 256) {
    int t   = i / (NH * 36);
    int rem = i - t * (NH * 36);
    int h   = rem / 36;
    int d2  = rem - h * 36;
    float a  = ang[s * 36 + d2];
    float cs = cosf(a), sn = sinf(a);
    bf16* p = row + t * ED + h * HD + d2;
    float x1 = __bfloat162float(p[0]);
    float x2 = __bfloat162float(p[36]);
    p[0]  = __float2bfloat16(x1 * cs - x2 * sn);
    p[36] = __float2bfloat16(x2 * cs + x1 * sn);
  }
}

// ---------------- V transpose -> global V^T[h][d][s] with per-row bank rotation ----
__global__ __launch_bounds__(256, 4) void transpose_v(const bf16* __restrict__ qkv,
                                                      bf16* __restrict__ vt) {
  const int h  = blockIdx.x & 15;
  const int st = blockIdx.x >> 4;
  const int s0 = st * 64;
  const int tid = threadIdx.x;
  __shared__ __align__(16) bf16 Lt[72 * 72];

  const bf16* src = qkv + (size_t)s0 * QKVN + 2 * ED + h * HD;
  for (int c = tid; c < 576; c += 256) {
    int j = c / 9, m9 = c - j * 9;
    int d0 = m9 << 3;
    int jj = (j + (m9 << 3)) & 63;
    bf16x8 v = *reinterpret_cast<const bf16x8*>(src + (size_t)j * QKVN + d0);
    const unsigned short* u = reinterpret_cast<const unsigned short*>(&v);
#pragma unroll
    for (int e = 0; e < 8; ++e)
      Lt[(d0 + e) * 72 + jj] = __builtin_bit_cast(bf16, u[e]);
  }
  __syncthreads();

  bf16x8 ones8, zero8 = {};
  {
    unsigned short ob = f2bfbits(1.0f);
#pragma unroll
    for (int e = 0; e < 8; ++e) ones8[e] = __builtin_bit_cast(__bf16, ob);
  }
  bf16* dst = vt + (size_t)(h * VTROWS) * SEQ + s0;
  for (int c = tid; c < VTROWS * 8; c += 256) {
    int d = c >> 3, sc = c & 7;
    bf16x8 v;
    int og = sc;
    if (d < 72) {
      int col = (((sc + (d >> 3)) << 3)) & 63;
      v = *reinterpret_cast<const bf16x8*>(&Lt[d * 72 + col]);
      og = (sc + (d & 7)) & 7;
    } else {
      v = (d == 72) ? ones8 : zero8;
    }
    *reinterpret_cast<bf16x8*>(dst + (size_t)d * SEQ + (og << 3)) = v;
  }
}

// ---------------- flash attention v18 = R20 + round-half-up P convert ----------------
__global__ __launch_bounds__(256, 4) void attn(const bf16* __restrict__ qkv,
                                               const bf16* __restrict__ vt,
                                               bf16* __restrict__ ctx) {
  const int blk  = blockIdx.x;
  const int qt   = (blk >> 3) & 15;
  const int g    = (((blk >> 7) & 15) << 3) | (blk & 7);
  const int head = g & 15;
  const int seg  = g >> 4;
  const int q0   = seg * SEGLEN + qt * 128;

  const int tid = threadIdx.x, lane = tid & 63, w = tid >> 6;
  const int row15 = lane & 15, hi = lane >> 4, koff = hi << 3;

  __shared__ __align__(16) bf16 Ks[64 * 72];
  __shared__ __align__(16) bf16 Vt[VTROWS * 64];
  __shared__ __align__(16) bf16 Ps[128 * 72];

  const bf16* Qg  = qkv + (size_t)q0 * QKVN + head * HD;
  const bf16* Kg  = qkv + (size_t)(seg * SEGLEN) * QKVN + ED + head * HD;
  const bf16* Vtg = vt + (size_t)(head * VTROWS) * SEQ + seg * SEGLEN;

  const bf16x8 zero8 = {};
  bf16x8 aq[2][3];
#pragma unroll
  for (int m = 0; m < 2; ++m) {
    const bf16* qrow = Qg + (size_t)(w * 32 + m * 16 + row15) * QKVN;
    aq[m][0] = *reinterpret_cast<const bf16x8*>(qrow + koff);
    aq[m][1] = *reinterpret_cast<const bf16x8*>(qrow + 32 + koff);
    aq[m][2] = (hi == 0) ? *reinterpret_cast<const bf16x8*>(qrow + 64) : zero8;
  }

  f32x4 oacc[2][5] = {};
  const float c2 = 0.11785113019775793f * 1.4426950408889634f;  // scale * log2(e)

  auto stage_k = [&](int kt2) {
    const bf16* Kt = Kg + (size_t)kt2 * 64 * QKVN;
    char* KsB = (char*)Ks;
    for (int gq = w; gq < 9; gq += 4) {
      int chunk = gq * 64 + lane;
      int row = chunk / 9;
      int cc  = chunk - row * 9;
      gload_lds16(Kt + (size_t)row * QKVN + cc * 8, KsB + gq * 1024);
    }
  };

  auto stage_v = [&](int kt2) {
    const bf16* Vsrc = Vtg + (size_t)kt2 * 64;
    char* VsB = (char*)Vt;
    for (int i = w; i < 10; i += 4) {
      int c = i * 64 + lane;
      int d = c >> 3, g8 = c & 7;
      gload_lds16(Vsrc + (size_t)d * SEQ + g8 * 8, VsB + i * 1024);
    }
  };

  auto qkt_soft = [&]() {
    f32x4 s[2][4] = {};
    __builtin_amdgcn_s_setprio(1);
#pragma unroll
    for (int ks = 0; ks < 2; ++ks) {
#pragma unroll
      for (int n = 0; n < 4; ++n) {
        bf16x8 bk = *reinterpret_cast<const bf16x8*>(&Ks[(n * 16 + row15) * 72 + ks * 32 + koff]);
        s[0][n] = __builtin_amdgcn_mfma_f32_16x16x32_bf16(aq[0][ks], bk, s[0][n], 0, 0, 0);
        s[1][n] = __builtin_amdgcn_mfma_f32_16x16x32_bf16(aq[1][ks], bk, s[1][n], 0, 0, 0);
      }
    }
#pragma unroll
    for (int n = 0; n < 4; ++n) {
      bf16x8 bk = (hi == 0) ? *reinterpret_cast<const bf16x8*>(&Ks[(n * 16 + row15) * 72 + 64]) : zero8;
      s[0][n] = __builtin_amdgcn_mfma_f32_16x16x32_bf16(aq[0][2], bk, s[0][n], 0, 0, 0);
      s[1][n] = __builtin_amdgcn_mfma_f32_16x16x32_bf16(aq[1][2], bk, s[1][n], 0, 0, 0);
    }
    __builtin_amdgcn_s_setprio(0);
    const int prow_base = w * 32 + hi * 4;
#pragma unroll
    for (int m = 0; m < 2; ++m)
#pragma unroll
      for (int n = 0; n < 4; ++n)
#pragma unroll
        for (int r = 0; r < 4; ++r) {
          float p = fexp2(fmaf(s[m][n][r], c2, -4.0f));
          Ps[(prow_base + m * 16 + r) * 72 + n * 16 + row15] =
              __builtin_bit_cast(bf16, f2bf_rhu(p));
        }
  };

  auto pv = [&]() {
    __builtin_amdgcn_s_setprio(1);
#pragma unroll
    for (int ks = 0; ks < 2; ++ks) {
      bf16x8 ap0 = *reinterpret_cast<const bf16x8*>(&Ps[(w * 32 + row15) * 72 + ks * 32 + koff]);
      bf16x8 ap1 = *reinterpret_cast<const bf16x8*>(&Ps[(w * 32 + 16 + row15) * 72 + ks * 32 + koff]);
#pragma unroll
      for (int n = 0; n < 5; ++n) {
        const int vrow = n * 16 + row15;
        const int cA = ((((ks << 2) + hi + (vrow & 7)) & 7) << 3);
        bf16x8 bv = *reinterpret_cast<const bf16x8*>(&Vt[vrow * 64 + cA]);
        oacc[0][n] = __builtin_amdgcn_mfma_f32_16x16x32_bf16(ap0, bv, oacc[0][n], 0, 0, 0);
        oacc[1][n] = __builtin_amdgcn_mfma_f32_16x16x32_bf16(ap1, bv, oacc[1][n], 0, 0, 0);
      }
    }
    __builtin_amdgcn_s_setprio(0);
  };

  stage_k(0);
  stage_v(0);
  for (int kt = 0; kt < NT; ++kt) {
    __syncthreads();   // BAR_A: staging(kt) drained
    qkt_soft();
    pv();
    __syncthreads();   // BAR_B: all waves done reading Ks/Vt of kt
    if (kt + 1 < NT) {
      stage_k(kt + 1);
      stage_v(kt + 1);
    }
  }

#pragma unroll
  for (int m = 0; m < 2; ++m) {
#pragma unroll
    for (int r = 0; r < 4; ++r) {
      float l = __shfl(oacc[m][4][r], (lane & 48) + 8);
      float inv = 1.0f / l;
#pragma unroll
      for (int n = 0; n < 5; ++n) {
        const int d = n * 16 + row15;
        if (d < HD) {
          const int row = q0 + w * 32 + m * 16 + hi * 4 + r;
          ctx[(size_t)row * ED + head * HD + d] = __float2bfloat16(oacc[m][n][r] * inv);
        }
      }
    }
  }
}

// ---------------- launch ----------------
extern "C" void kernel_launch(void* const* d_in, const int* in_sizes, int n_in,
                              void* d_out, int out_size, void* d_ws, size_t ws_size,
                              hipStream_t stream) {
  const float* hidden = (const float*)d_in[0];
  const float* qkv_w  = (const float*)d_in[1];
  const float* qkv_b  = (const float*)d_in[2];
  const float* out_w  = (const float*)d_in[3];
  const float* out_b  = (const float*)d_in[4];
  const float* rope   = (const float*)d_in[5];

  const size_t SZ_QKV = (size_t)SEQ * QKVN * 2;
  const size_t SZ_X   = (size_t)SEQ * ED * 2;
  const size_t SZ_W   = (size_t)QKVN * ED * 2;
  const size_t SZ_VT  = (size_t)NH * VTROWS * SEQ * 2;
  const size_t NEED   = SZ_QKV + SZ_X + SZ_W + SZ_VT;
  if (ws_size < NEED) return;

  char* ws = (char*)d_ws;
  bf16* qkvbf = (bf16*)(ws);
  bf16* Xbf   = (bf16*)(ws + SZ_QKV);
  bf16* Wbf   = (bf16*)(ws + SZ_QKV + SZ_X);
  bf16* vtb   = (bf16*)(ws + SZ_QKV + SZ_X + SZ_W);

  cvt_f32_bf16<<<(SEQ * ED / 4 + 255) / 256, 256, 0, stream>>>(hidden, Xbf, SEQ * ED / 4);
  cvt_f32_bf16<<<(QKVN * ED / 4 + 255) / 256, 256, 0, stream>>>(qkv_w, Wbf, QKVN * ED / 4);

  gemm_bt<<<(SEQ / 128) * (QKVN / 128), 256, 0, stream>>>(Xbf, Wbf, qkv_b, qkvbf,
                                                          SEQ, QKVN, ED, 1);

  cvt_f32_bf16<<<(ED * ED / 4 + 255) / 256, 256, 0, stream>>>(out_w, Wbf, ED * ED / 4);

  rope_inplace<<<SEQ, 256, 0, stream>>>(qkvbf, rope);

  transpose_v<<<NH * (SEQ / 64), 256, 0, stream>>>(qkvbf, vtb);

  attn<<<NSEG * NH * (SEGLEN / 128), 256, 0, stream>>>(qkvbf, vtb, Xbf);

  gemm_bt<<<(SEQ / 128) * (ED / 128), 256, 0, stream>>>(Xbf, Wbf, out_b, d_out,
                                                        SEQ, ED, ED, 0);
}

// Round 23
// 517.480 us; speedup vs baseline: 1.8276x; 1.0045x over previous
//
#include <hip/hip_runtime.h>
#include <hip/hip_bf16.h>
#include <cstdint>

#define SEQ   16384
#define ED    1152
#define NH    16
#define HD    72
#define NSEG  8
#define SEGLEN 2048
#define QKVN  3456
#define NT    (SEGLEN / 64)
#define VTROWS 80

typedef __bf16 bf16x8 __attribute__((ext_vector_type(8)));
typedef float  f32x4  __attribute__((ext_vector_type(4)));
typedef __hip_bfloat16 bf16;

__device__ __forceinline__ unsigned short f2bfbits(float f) {
  bf16 h = __float2bfloat16(f);
  return __builtin_bit_cast(unsigned short, h);
}

__device__ __forceinline__ float fexp2(float x) {
#if __has_builtin(__builtin_amdgcn_exp2f)
  return __builtin_amdgcn_exp2f(x);
#else
  return exp2f(x);
#endif
}

// round-half-up f32->bf16 (2 VALU); valid for finite positive p (never NaN here)
__device__ __forceinline__ unsigned short f2bf_rhu(float f) {
  unsigned int b = __builtin_bit_cast(unsigned int, f);
  return (unsigned short)((b + 0x8000u) >> 16);
}

__device__ __forceinline__ void gload_lds16(const void* g, void* l) {
  __builtin_amdgcn_global_load_lds(
      (__attribute__((address_space(1))) void*)(void*)g,
      (__attribute__((address_space(3))) void*)l, 16, 0, 0);
}

// ---------------- prep kernels ----------------
__global__ __launch_bounds__(256) void cvt_f32_bf16(const float* __restrict__ in,
                                                    bf16* __restrict__ out, int n4) {
  int i = blockIdx.x * 256 + threadIdx.x;
  if (i >= n4) return;
  float4 v = reinterpret_cast<const float4*>(in)[i];
  ushort4 o;
  o.x = f2bfbits(v.x); o.y = f2bfbits(v.y); o.z = f2bfbits(v.z); o.w = f2bfbits(v.w);
  reinterpret_cast<ushort4*>(out)[i] = o;
}

// ---------------- GEMM: C[M][N] = A[M][K]*B[N][K]^T + bias (BK=64, R20-verified) ----
__global__ __launch_bounds__(256) void gemm_bt(const bf16* __restrict__ A,
                                               const bf16* __restrict__ B,
                                               const float* __restrict__ bias,
                                               void* __restrict__ Cout,
                                               int M, int N, int K, int out_bf16) {
  __shared__ __align__(16) bf16 As[2 * 128 * 32];
  __shared__ __align__(16) bf16 Bs[2 * 128 * 32];
  const int nt   = N >> 7;
  const int nwg  = gridDim.x;
  const int cpx  = nwg >> 3;
  const int bid  = blockIdx.x;
  const int swz  = (bid & 7) * cpx + (bid >> 3);
  const int bm   = swz / nt;
  const int bn   = swz % nt;
  const int tid  = threadIdx.x;
  const int lane = tid & 63;
  const int wave = tid >> 6;
  const int wr   = wave >> 1, wc = wave & 1;

  const bf16* Ab = A + (size_t)(bm * 128) * K;
  const bf16* Bb = B + (size_t)(bn * 128) * K;

  char* AsB = (char*)As;
  char* BsB = (char*)Bs;

  const int row15 = lane & 15;
  const int koff  = (lane >> 4) << 3;
  const int srow  = lane >> 2;
  const int scol  = (lane & 3) << 3;

  f32x4 acc[4][4] = {};

  for (int k0 = 0; k0 < K; k0 += 64) {
#pragma unroll
    for (int i = wave; i < 16; i += 4) {
      const int kk = i >> 3, ib = i & 7;
      gload_lds16(Ab + (size_t)(ib * 16 + srow) * K + k0 + kk * 32 + scol, AsB + i * 1024);
      gload_lds16(Bb + (size_t)(ib * 16 + srow) * K + k0 + kk * 32 + scol, BsB + i * 1024);
    }
    __syncthreads();
#pragma unroll
    for (int kk = 0; kk < 2; ++kk) {
      bf16x8 a[4], b[4];
#pragma unroll
      for (int mi = 0; mi < 4; ++mi)
        a[mi] = *reinterpret_cast<const bf16x8*>(&As[kk * 4096 + (wr * 64 + mi * 16 + row15) * 32 + koff]);
#pragma unroll
      for (int ni = 0; ni < 4; ++ni)
        b[ni] = *reinterpret_cast<const bf16x8*>(&Bs[kk * 4096 + (wc * 64 + ni * 16 + row15) * 32 + koff]);
#pragma unroll
      for (int mi = 0; mi < 4; ++mi)
#pragma unroll
        for (int ni = 0; ni < 4; ++ni)
          acc[mi][ni] = __builtin_amdgcn_mfma_f32_16x16x32_bf16(a[mi], b[ni], acc[mi][ni], 0, 0, 0);
    }
    __syncthreads();
  }

  const int crow = bm * 128 + wr * 64 + (lane >> 4) * 4;
  const int ccol = bn * 128 + wc * 64 + row15;
#pragma unroll
  for (int mi = 0; mi < 4; ++mi)
#pragma unroll
    for (int ni = 0; ni < 4; ++ni) {
      const int col = ccol + ni * 16;
      const float bv = bias[col];
#pragma unroll
      for (int r = 0; r < 4; ++r) {
        const int row = crow + mi * 16 + r;
        float v = acc[mi][ni][r] + bv;
        if (out_bf16)
          reinterpret_cast<bf16*>(Cout)[(size_t)row * N + col] = __float2bfloat16(v);
        else
          reinterpret_cast<float*>(Cout)[(size_t)row * N + col] = v;
      }
    }
}

// ---------------- RoPE in-place on qkv [s][3456] ----------------
__global__ __launch_bounds__(256) void rope_inplace(bf16* __restrict__ qkv,
                                                    const float* __restrict__ ang) {
  const int s = blockIdx.x;
  bf16* row = qkv + (size_t)s * QKVN;
  for (int i = threadIdx.x; i < 2 * NH * 36; i += 256) {
    int t   = i / (NH * 36);
    int rem = i - t * (NH * 36);
    int h   = rem / 36;
    int d2  = rem - h * 36;
    float a  = ang[s * 36 + d2];
    float cs = cosf(a), sn = sinf(a);
    bf16* p = row + t * ED + h * HD + d2;
    float x1 = __bfloat162float(p[0]);
    float x2 = __bfloat162float(p[36]);
    p[0]  = __float2bfloat16(x1 * cs - x2 * sn);
    p[36] = __float2bfloat16(x2 * cs + x1 * sn);
  }
}

// ---------------- V transpose -> global V^T[h][d][s] with per-row bank rotation ----
__global__ __launch_bounds__(256, 4) void transpose_v(const bf16* __restrict__ qkv,
                                                      bf16* __restrict__ vt) {
  const int h  = blockIdx.x & 15;
  const int st = blockIdx.x >> 4;
  const int s0 = st * 64;
  const int tid = threadIdx.x;
  __shared__ __align__(16) bf16 Lt[72 * 72];

  const bf16* src = qkv + (size_t)s0 * QKVN + 2 * ED + h * HD;
  for (int c = tid; c < 576; c += 256) {
    int j = c / 9, m9 = c - j * 9;
    int d0 = m9 << 3;
    int jj = (j + (m9 << 3)) & 63;
    bf16x8 v = *reinterpret_cast<const bf16x8*>(src + (size_t)j * QKVN + d0);
    const unsigned short* u = reinterpret_cast<const unsigned short*>(&v);
#pragma unroll
    for (int e = 0; e < 8; ++e)
      Lt[(d0 + e) * 72 + jj] = __builtin_bit_cast(bf16, u[e]);
  }
  __syncthreads();

  bf16x8 ones8, zero8 = {};
  {
    unsigned short ob = f2bfbits(1.0f);
#pragma unroll
    for (int e = 0; e < 8; ++e) ones8[e] = __builtin_bit_cast(__bf16, ob);
  }
  bf16* dst = vt + (size_t)(h * VTROWS) * SEQ + s0;
  for (int c = tid; c < VTROWS * 8; c += 256) {
    int d = c >> 3, sc = c & 7;
    bf16x8 v;
    int og = sc;
    if (d < 72) {
      int col = (((sc + (d >> 3)) << 3)) & 63;
      v = *reinterpret_cast<const bf16x8*>(&Lt[d * 72 + col]);
      og = (sc + (d & 7)) & 7;
    } else {
      v = (d == 72) ? ones8 : zero8;
    }
    *reinterpret_cast<bf16x8*>(dst + (size_t)d * SEQ + (og << 3)) = v;
  }
}

// ---------------- flash attention v19 = R22 + QBLK 256 (8 waves) ----------------
// Per-wave structure identical to the verified 128-q-tile kernel; only the block
// now covers 256 q-rows -> K/V staging, L2 reads, and barriers amortized 2x.
__global__ __launch_bounds__(512, 4) void attn(const bf16* __restrict__ qkv,
                                               const bf16* __restrict__ vt,
                                               bf16* __restrict__ ctx) {
  const int blk  = blockIdx.x;
  // swizzle: all 8 q-tiles of one (seg,head) land on one XCD for K/V L2 locality
  const int qt   = (blk >> 3) & 7;
  const int g    = (((blk >> 6) & 15) << 3) | (blk & 7);
  const int head = g & 15;
  const int seg  = g >> 4;
  const int q0   = seg * SEGLEN + qt * 256;

  const int tid = threadIdx.x, lane = tid & 63, w = tid >> 6;   // w in 0..7
  const int row15 = lane & 15, hi = lane >> 4, koff = hi << 3;

  __shared__ __align__(16) bf16 Ks[64 * 72];
  __shared__ __align__(16) bf16 Vt[VTROWS * 64];
  __shared__ __align__(16) bf16 Ps[256 * 72];   // per-wave exclusive 32-row slices

  const bf16* Qg  = qkv + (size_t)q0 * QKVN + head * HD;
  const bf16* Kg  = qkv + (size_t)(seg * SEGLEN) * QKVN + ED + head * HD;
  const bf16* Vtg = vt + (size_t)(head * VTROWS) * SEQ + seg * SEGLEN;

  const bf16x8 zero8 = {};
  bf16x8 aq[2][3];
#pragma unroll
  for (int m = 0; m < 2; ++m) {
    const bf16* qrow = Qg + (size_t)(w * 32 + m * 16 + row15) * QKVN;
    aq[m][0] = *reinterpret_cast<const bf16x8*>(qrow + koff);
    aq[m][1] = *reinterpret_cast<const bf16x8*>(qrow + 32 + koff);
    aq[m][2] = (hi == 0) ? *reinterpret_cast<const bf16x8*>(qrow + 64) : zero8;
  }

  f32x4 oacc[2][5] = {};
  const float c2 = 0.11785113019775793f * 1.4426950408889634f;  // scale * log2(e)

  auto stage_k = [&](int kt2) {
    const bf16* Kt = Kg + (size_t)kt2 * 64 * QKVN;
    char* KsB = (char*)Ks;
    for (int gq = w; gq < 9; gq += 8) {
      int chunk = gq * 64 + lane;
      int row = chunk / 9;
      int cc  = chunk - row * 9;
      gload_lds16(Kt + (size_t)row * QKVN + cc * 8, KsB + gq * 1024);
    }
  };

  auto stage_v = [&](int kt2) {
    const bf16* Vsrc = Vtg + (size_t)kt2 * 64;
    char* VsB = (char*)Vt;
    for (int i = w; i < 10; i += 8) {
      int c = i * 64 + lane;
      int d = c >> 3, g8 = c & 7;
      gload_lds16(Vsrc + (size_t)d * SEQ + g8 * 8, VsB + i * 1024);
    }
  };

  auto qkt_soft = [&]() {
    f32x4 s[2][4] = {};
    __builtin_amdgcn_s_setprio(1);
#pragma unroll
    for (int ks = 0; ks < 2; ++ks) {
#pragma unroll
      for (int n = 0; n < 4; ++n) {
        bf16x8 bk = *reinterpret_cast<const bf16x8*>(&Ks[(n * 16 + row15) * 72 + ks * 32 + koff]);
        s[0][n] = __builtin_amdgcn_mfma_f32_16x16x32_bf16(aq[0][ks], bk, s[0][n], 0, 0, 0);
        s[1][n] = __builtin_amdgcn_mfma_f32_16x16x32_bf16(aq[1][ks], bk, s[1][n], 0, 0, 0);
      }
    }
#pragma unroll
    for (int n = 0; n < 4; ++n) {
      bf16x8 bk = (hi == 0) ? *reinterpret_cast<const bf16x8*>(&Ks[(n * 16 + row15) * 72 + 64]) : zero8;
      s[0][n] = __builtin_amdgcn_mfma_f32_16x16x32_bf16(aq[0][2], bk, s[0][n], 0, 0, 0);
      s[1][n] = __builtin_amdgcn_mfma_f32_16x16x32_bf16(aq[1][2], bk, s[1][n], 0, 0, 0);
    }
    __builtin_amdgcn_s_setprio(0);
    const int prow_base = w * 32 + hi * 4;
#pragma unroll
    for (int m = 0; m < 2; ++m)
#pragma unroll
      for (int n = 0; n < 4; ++n)
#pragma unroll
        for (int r = 0; r < 4; ++r) {
          float p = fexp2(fmaf(s[m][n][r], c2, -4.0f));
          Ps[(prow_base + m * 16 + r) * 72 + n * 16 + row15] =
              __builtin_bit_cast(bf16, f2bf_rhu(p));
        }
  };

  auto pv = [&]() {
    __builtin_amdgcn_s_setprio(1);
#pragma unroll
    for (int ks = 0; ks < 2; ++ks) {
      bf16x8 ap0 = *reinterpret_cast<const bf16x8*>(&Ps[(w * 32 + row15) * 72 + ks * 32 + koff]);
      bf16x8 ap1 = *reinterpret_cast<const bf16x8*>(&Ps[(w * 32 + 16 + row15) * 72 + ks * 32 + koff]);
#pragma unroll
      for (int n = 0; n < 5; ++n) {
        const int vrow = n * 16 + row15;
        const int cA = ((((ks << 2) + hi + (vrow & 7)) & 7) << 3);
        bf16x8 bv = *reinterpret_cast<const bf16x8*>(&Vt[vrow * 64 + cA]);
        oacc[0][n] = __builtin_amdgcn_mfma_f32_16x16x32_bf16(ap0, bv, oacc[0][n], 0, 0, 0);
        oacc[1][n] = __builtin_amdgcn_mfma_f32_16x16x32_bf16(ap1, bv, oacc[1][n], 0, 0, 0);
      }
    }
    __builtin_amdgcn_s_setprio(0);
  };

  stage_k(0);
  stage_v(0);
  for (int kt = 0; kt < NT; ++kt) {
    __syncthreads();   // BAR_A: staging(kt) drained
    qkt_soft();
    pv();
    __syncthreads();   // BAR_B: all waves done reading Ks/Vt of kt
    if (kt + 1 < NT) {
      stage_k(kt + 1);
      stage_v(kt + 1);
    }
  }

#pragma unroll
  for (int m = 0; m < 2; ++m) {
#pragma unroll
    for (int r = 0; r < 4; ++r) {
      float l = __shfl(oacc[m][4][r], (lane & 48) + 8);
      float inv = 1.0f / l;
#pragma unroll
      for (int n = 0; n < 5; ++n) {
        const int d = n * 16 + row15;
        if (d < HD) {
          const int row = q0 + w * 32 + m * 16 + hi * 4 + r;
          ctx[(size_t)row * ED + head * HD + d] = __float2bfloat16(oacc[m][n][r] * inv);
        }
      }
    }
  }
}

// ---------------- launch ----------------
extern "C" void kernel_launch(void* const* d_in, const int* in_sizes, int n_in,
                              void* d_out, int out_size, void* d_ws, size_t ws_size,
                              hipStream_t stream) {
  const float* hidden = (const float*)d_in[0];
  const float* qkv_w  = (const float*)d_in[1];
  const float* qkv_b  = (const float*)d_in[2];
  const float* out_w  = (const float*)d_in[3];
  const float* out_b  = (const float*)d_in[4];
  const float* rope   = (const float*)d_in[5];

  const size_t SZ_QKV = (size_t)SEQ * QKVN * 2;
  const size_t SZ_X   = (size_t)SEQ * ED * 2;
  const size_t SZ_W   = (size_t)QKVN * ED * 2;
  const size_t SZ_VT  = (size_t)NH * VTROWS * SEQ * 2;
  const size_t NEED   = SZ_QKV + SZ_X + SZ_W + SZ_VT;
  if (ws_size < NEED) return;

  char* ws = (char*)d_ws;
  bf16* qkvbf = (bf16*)(ws);
  bf16* Xbf   = (bf16*)(ws + SZ_QKV);
  bf16* Wbf   = (bf16*)(ws + SZ_QKV + SZ_X);
  bf16* vtb   = (bf16*)(ws + SZ_QKV + SZ_X + SZ_W);

  cvt_f32_bf16<<<(SEQ * ED / 4 + 255) / 256, 256, 0, stream>>>(hidden, Xbf, SEQ * ED / 4);
  cvt_f32_bf16<<<(QKVN * ED / 4 + 255) / 256, 256, 0, stream>>>(qkv_w, Wbf, QKVN * ED / 4);

  gemm_bt<<<(SEQ / 128) * (QKVN / 128), 256, 0, stream>>>(Xbf, Wbf, qkv_b, qkvbf,
                                                          SEQ, QKVN, ED, 1);

  cvt_f32_bf16<<<(ED * ED / 4 + 255) / 256, 256, 0, stream>>>(out_w, Wbf, ED * ED / 4);

  rope_inplace<<<SEQ, 256, 0, stream>>>(qkvbf, rope);

  transpose_v<<<NH * (SEQ / 64), 256, 0, stream>>>(qkvbf, vtb);

  attn<<<NSEG * NH * (SEGLEN / 256), 512, 0, stream>>>(qkvbf, vtb, Xbf);

  gemm_bt<<<(SEQ / 128) * (ED / 128), 256, 0, stream>>>(Xbf, Wbf, out_b, d_out,
                                                        SEQ, ED, ED, 0);
}

// Round 24
// 516.310 us; speedup vs baseline: 1.8318x; 1.0023x over previous
//
#include <hip/hip_runtime.h>
#include <hip/hip_bf16.h>
#include <cstdint>

#define SEQ   16384
#define ED    1152
#define NH    16
#define HD    72
#define NSEG  8
#define SEGLEN 2048
#define QKVN  3456
#define NT    (SEGLEN / 64)
#define VTROWS 80
#define KSZ   (64 * 72)
#define VSZ   (VTROWS * 64)

typedef __bf16 bf16x8 __attribute__((ext_vector_type(8)));
typedef float  f32x4  __attribute__((ext_vector_type(4)));
typedef __hip_bfloat16 bf16;

__device__ __forceinline__ unsigned short f2bfbits(float f) {
  bf16 h = __float2bfloat16(f);
  return __builtin_bit_cast(unsigned short, h);
}

__device__ __forceinline__ float fexp2(float x) {
#if __has_builtin(__builtin_amdgcn_exp2f)
  return __builtin_amdgcn_exp2f(x);
#else
  return exp2f(x);
#endif
}

// round-half-up f32->bf16 (2 VALU); valid for finite positive p (never NaN here)
__device__ __forceinline__ unsigned short f2bf_rhu(float f) {
  unsigned int b = __builtin_bit_cast(unsigned int, f);
  return (unsigned short)((b + 0x8000u) >> 16);
}

__device__ __forceinline__ void gload_lds16(const void* g, void* l) {
  __builtin_amdgcn_global_load_lds(
      (__attribute__((address_space(1))) void*)(void*)g,
      (__attribute__((address_space(3))) void*)l, 16, 0, 0);
}

// ---------------- prep kernels ----------------
__global__ __launch_bounds__(256) void cvt_f32_bf16(const float* __restrict__ in,
                                                    bf16* __restrict__ out, int n4) {
  int i = blockIdx.x * 256 + threadIdx.x;
  if (i >= n4) return;
  float4 v = reinterpret_cast<const float4*>(in)[i];
  ushort4 o;
  o.x = f2bfbits(v.x); o.y = f2bfbits(v.y); o.z = f2bfbits(v.z); o.w = f2bfbits(v.w);
  reinterpret_cast<ushort4*>(out)[i] = o;
}

// ---------------- GEMM: C[M][N] = A[M][K]*B[N][K]^T + bias (BK=64, R20-verified) ----
__global__ __launch_bounds__(256) void gemm_bt(const bf16* __restrict__ A,
                                               const bf16* __restrict__ B,
                                               const float* __restrict__ bias,
                                               void* __restrict__ Cout,
                                               int M, int N, int K, int out_bf16) {
  __shared__ __align__(16) bf16 As[2 * 128 * 32];
  __shared__ __align__(16) bf16 Bs[2 * 128 * 32];
  const int nt   = N >> 7;
  const int nwg  = gridDim.x;
  const int cpx  = nwg >> 3;
  const int bid  = blockIdx.x;
  const int swz  = (bid & 7) * cpx + (bid >> 3);
  const int bm   = swz / nt;
  const int bn   = swz % nt;
  const int tid  = threadIdx.x;
  const int lane = tid & 63;
  const int wave = tid >> 6;
  const int wr   = wave >> 1, wc = wave & 1;

  const bf16* Ab = A + (size_t)(bm * 128) * K;
  const bf16* Bb = B + (size_t)(bn * 128) * K;

  char* AsB = (char*)As;
  char* BsB = (char*)Bs;

  const int row15 = lane & 15;
  const int koff  = (lane >> 4) << 3;
  const int srow  = lane >> 2;
  const int scol  = (lane & 3) << 3;

  f32x4 acc[4][4] = {};

  for (int k0 = 0; k0 < K; k0 += 64) {
#pragma unroll
    for (int i = wave; i < 16; i += 4) {
      const int kk = i >> 3, ib = i & 7;
      gload_lds16(Ab + (size_t)(ib * 16 + srow) * K + k0 + kk * 32 + scol, AsB + i * 1024);
      gload_lds16(Bb + (size_t)(ib * 16 + srow) * K + k0 + kk * 32 + scol, BsB + i * 1024);
    }
    __syncthreads();
#pragma unroll
    for (int kk = 0; kk < 2; ++kk) {
      bf16x8 a[4], b[4];
#pragma unroll
      for (int mi = 0; mi < 4; ++mi)
        a[mi] = *reinterpret_cast<const bf16x8*>(&As[kk * 4096 + (wr * 64 + mi * 16 + row15) * 32 + koff]);
#pragma unroll
      for (int ni = 0; ni < 4; ++ni)
        b[ni] = *reinterpret_cast<const bf16x8*>(&Bs[kk * 4096 + (wc * 64 + ni * 16 + row15) * 32 + koff]);
#pragma unroll
      for (int mi = 0; mi < 4; ++mi)
#pragma unroll
        for (int ni = 0; ni < 4; ++ni)
          acc[mi][ni] = __builtin_amdgcn_mfma_f32_16x16x32_bf16(a[mi], b[ni], acc[mi][ni], 0, 0, 0);
    }
    __syncthreads();
  }

  const int crow = bm * 128 + wr * 64 + (lane >> 4) * 4;
  const int ccol = bn * 128 + wc * 64 + row15;
#pragma unroll
  for (int mi = 0; mi < 4; ++mi)
#pragma unroll
    for (int ni = 0; ni < 4; ++ni) {
      const int col = ccol + ni * 16;
      const float bv = bias[col];
#pragma unroll
      for (int r = 0; r < 4; ++r) {
        const int row = crow + mi * 16 + r;
        float v = acc[mi][ni][r] + bv;
        if (out_bf16)
          reinterpret_cast<bf16*>(Cout)[(size_t)row * N + col] = __float2bfloat16(v);
        else
          reinterpret_cast<float*>(Cout)[(size_t)row * N + col] = v;
      }
    }
}

// ---------------- RoPE in-place on qkv [s][3456] ----------------
__global__ __launch_bounds__(256) void rope_inplace(bf16* __restrict__ qkv,
                                                    const float* __restrict__ ang) {
  const int s = blockIdx.x;
  bf16* row = qkv + (size_t)s * QKVN;
  for (int i = threadIdx.x; i < 2 * NH * 36; i += 256) {
    int t   = i / (NH * 36);
    int rem = i - t * (NH * 36);
    int h   = rem / 36;
    int d2  = rem - h * 36;
    float a  = ang[s * 36 + d2];
    float cs = cosf(a), sn = sinf(a);
    bf16* p = row + t * ED + h * HD + d2;
    float x1 = __bfloat162float(p[0]);
    float x2 = __bfloat162float(p[36]);
    p[0]  = __float2bfloat16(x1 * cs - x2 * sn);
    p[36] = __float2bfloat16(x2 * cs + x1 * sn);
  }
}

// ---------------- V transpose -> global V^T[h][d][s] with per-row bank rotation ----
__global__ __launch_bounds__(256, 4) void transpose_v(const bf16* __restrict__ qkv,
                                                      bf16* __restrict__ vt) {
  const int h  = blockIdx.x & 15;
  const int st = blockIdx.x >> 4;
  const int s0 = st * 64;
  const int tid = threadIdx.x;
  __shared__ __align__(16) bf16 Lt[72 * 72];

  const bf16* src = qkv + (size_t)s0 * QKVN + 2 * ED + h * HD;
  for (int c = tid; c < 576; c += 256) {
    int j = c / 9, m9 = c - j * 9;
    int d0 = m9 << 3;
    int jj = (j + (m9 << 3)) & 63;
    bf16x8 v = *reinterpret_cast<const bf16x8*>(src + (size_t)j * QKVN + d0);
    const unsigned short* u = reinterpret_cast<const unsigned short*>(&v);
#pragma unroll
    for (int e = 0; e < 8; ++e)
      Lt[(d0 + e) * 72 + jj] = __builtin_bit_cast(bf16, u[e]);
  }
  __syncthreads();

  bf16x8 ones8, zero8 = {};
  {
    unsigned short ob = f2bfbits(1.0f);
#pragma unroll
    for (int e = 0; e < 8; ++e) ones8[e] = __builtin_bit_cast(__bf16, ob);
  }
  bf16* dst = vt + (size_t)(h * VTROWS) * SEQ + s0;
  for (int c = tid; c < VTROWS * 8; c += 256) {
    int d = c >> 3, sc = c & 7;
    bf16x8 v;
    int og = sc;
    if (d < 72) {
      int col = (((sc + (d >> 3)) << 3)) & 63;
      v = *reinterpret_cast<const bf16x8*>(&Lt[d * 72 + col]);
      og = (sc + (d & 7)) & 7;
    } else {
      v = (d == 72) ? ones8 : zero8;
    }
    *reinterpret_cast<bf16x8*>(dst + (size_t)d * SEQ + (og << 3)) = v;
  }
}

// ---------------- flash attention v20 = R23 + dbuf staging, 1 barrier/tile ----------------
// Staging issued at TOP of iteration into buf[(kt+1)&1] -> HBM/L2 latency hides under
// the full qkt+softmax+pv of tile kt; drained by the next barrier's vmcnt(0).
__global__ __launch_bounds__(512, 4) void attn(const bf16* __restrict__ qkv,
                                               const bf16* __restrict__ vt,
                                               bf16* __restrict__ ctx) {
  const int blk  = blockIdx.x;
  // swizzle: all 8 q-tiles of one (seg,head) land on one XCD for K/V L2 locality
  const int qt   = (blk >> 3) & 7;
  const int g    = (((blk >> 6) & 15) << 3) | (blk & 7);
  const int head = g & 15;
  const int seg  = g >> 4;
  const int q0   = seg * SEGLEN + qt * 256;

  const int tid = threadIdx.x, lane = tid & 63, w = tid >> 6;   // w in 0..7
  const int row15 = lane & 15, hi = lane >> 4, koff = hi << 3;

  __shared__ __align__(16) bf16 Ks[2 * KSZ];
  __shared__ __align__(16) bf16 Vt[2 * VSZ];
  __shared__ __align__(16) bf16 Ps[256 * 72];   // per-wave exclusive 32-row slices

  const bf16* Qg  = qkv + (size_t)q0 * QKVN + head * HD;
  const bf16* Kg  = qkv + (size_t)(seg * SEGLEN) * QKVN + ED + head * HD;
  const bf16* Vtg = vt + (size_t)(head * VTROWS) * SEQ + seg * SEGLEN;

  const bf16x8 zero8 = {};
  bf16x8 aq[2][3];
#pragma unroll
  for (int m = 0; m < 2; ++m) {
    const bf16* qrow = Qg + (size_t)(w * 32 + m * 16 + row15) * QKVN;
    aq[m][0] = *reinterpret_cast<const bf16x8*>(qrow + koff);
    aq[m][1] = *reinterpret_cast<const bf16x8*>(qrow + 32 + koff);
    aq[m][2] = (hi == 0) ? *reinterpret_cast<const bf16x8*>(qrow + 64) : zero8;
  }

  f32x4 oacc[2][5] = {};
  const float c2 = 0.11785113019775793f * 1.4426950408889634f;  // scale * log2(e)

  auto stage_k = [&](int kt2) {
    const bf16* Kt = Kg + (size_t)kt2 * 64 * QKVN;
    char* KsB = (char*)(Ks + (kt2 & 1) * KSZ);
    for (int gq = w; gq < 9; gq += 8) {
      int chunk = gq * 64 + lane;
      int row = chunk / 9;
      int cc  = chunk - row * 9;
      gload_lds16(Kt + (size_t)row * QKVN + cc * 8, KsB + gq * 1024);
    }
  };

  auto stage_v = [&](int kt2) {
    const bf16* Vsrc = Vtg + (size_t)kt2 * 64;
    char* VsB = (char*)(Vt + (kt2 & 1) * VSZ);
    for (int i = w; i < 10; i += 8) {
      int c = i * 64 + lane;
      int d = c >> 3, g8 = c & 7;
      gload_lds16(Vsrc + (size_t)d * SEQ + g8 * 8, VsB + i * 1024);
    }
  };

  auto qkt_soft = [&](int sel) {
    const bf16* ks = Ks + sel * KSZ;
    f32x4 s[2][4] = {};
    __builtin_amdgcn_s_setprio(1);
#pragma unroll
    for (int kc = 0; kc < 2; ++kc) {
#pragma unroll
      for (int n = 0; n < 4; ++n) {
        bf16x8 bk = *reinterpret_cast<const bf16x8*>(&ks[(n * 16 + row15) * 72 + kc * 32 + koff]);
        s[0][n] = __builtin_amdgcn_mfma_f32_16x16x32_bf16(aq[0][kc], bk, s[0][n], 0, 0, 0);
        s[1][n] = __builtin_amdgcn_mfma_f32_16x16x32_bf16(aq[1][kc], bk, s[1][n], 0, 0, 0);
      }
    }
#pragma unroll
    for (int n = 0; n < 4; ++n) {
      bf16x8 bk = (hi == 0) ? *reinterpret_cast<const bf16x8*>(&ks[(n * 16 + row15) * 72 + 64]) : zero8;
      s[0][n] = __builtin_amdgcn_mfma_f32_16x16x32_bf16(aq[0][2], bk, s[0][n], 0, 0, 0);
      s[1][n] = __builtin_amdgcn_mfma_f32_16x16x32_bf16(aq[1][2], bk, s[1][n], 0, 0, 0);
    }
    __builtin_amdgcn_s_setprio(0);
    const int prow_base = w * 32 + hi * 4;
#pragma unroll
    for (int m = 0; m < 2; ++m)
#pragma unroll
      for (int n = 0; n < 4; ++n)
#pragma unroll
        for (int r = 0; r < 4; ++r) {
          float p = fexp2(fmaf(s[m][n][r], c2, -4.0f));
          Ps[(prow_base + m * 16 + r) * 72 + n * 16 + row15] =
              __builtin_bit_cast(bf16, f2bf_rhu(p));
        }
  };

  auto pv = [&](int sel) {
    const bf16* vb = Vt + sel * VSZ;
    __builtin_amdgcn_s_setprio(1);
#pragma unroll
    for (int ks2 = 0; ks2 < 2; ++ks2) {
      bf16x8 ap0 = *reinterpret_cast<const bf16x8*>(&Ps[(w * 32 + row15) * 72 + ks2 * 32 + koff]);
      bf16x8 ap1 = *reinterpret_cast<const bf16x8*>(&Ps[(w * 32 + 16 + row15) * 72 + ks2 * 32 + koff]);
#pragma unroll
      for (int n = 0; n < 5; ++n) {
        const int vrow = n * 16 + row15;
        const int cA = ((((ks2 << 2) + hi + (vrow & 7)) & 7) << 3);
        bf16x8 bv = *reinterpret_cast<const bf16x8*>(&vb[vrow * 64 + cA]);
        oacc[0][n] = __builtin_amdgcn_mfma_f32_16x16x32_bf16(ap0, bv, oacc[0][n], 0, 0, 0);
        oacc[1][n] = __builtin_amdgcn_mfma_f32_16x16x32_bf16(ap1, bv, oacc[1][n], 0, 0, 0);
      }
    }
    __builtin_amdgcn_s_setprio(0);
  };

  stage_k(0);
  stage_v(0);
  for (int kt = 0; kt < NT; ++kt) {
    __syncthreads();   // stage(kt) drained (vmcnt0 at barrier); prev readers of buf[(kt+1)&1] done
    if (kt + 1 < NT) {
      stage_k(kt + 1); // issue EARLY -> latency hides under qkt+softmax+pv below
      stage_v(kt + 1);
    }
    qkt_soft(kt & 1);
    pv(kt & 1);
  }

#pragma unroll
  for (int m = 0; m < 2; ++m) {
#pragma unroll
    for (int r = 0; r < 4; ++r) {
      float l = __shfl(oacc[m][4][r], (lane & 48) + 8);
      float inv = 1.0f / l;
#pragma unroll
      for (int n = 0; n < 5; ++n) {
        const int d = n * 16 + row15;
        if (d < HD) {
          const int row = q0 + w * 32 + m * 16 + hi * 4 + r;
          ctx[(size_t)row * ED + head * HD + d] = __float2bfloat16(oacc[m][n][r] * inv);
        }
      }
    }
  }
}

// ---------------- launch ----------------
extern "C" void kernel_launch(void* const* d_in, const int* in_sizes, int n_in,
                              void* d_out, int out_size, void* d_ws, size_t ws_size,
                              hipStream_t stream) {
  const float* hidden = (const float*)d_in[0];
  const float* qkv_w  = (const float*)d_in[1];
  const float* qkv_b  = (const float*)d_in[2];
  const float* out_w  = (const float*)d_in[3];
  const float* out_b  = (const float*)d_in[4];
  const float* rope   = (const float*)d_in[5];

  const size_t SZ_QKV = (size_t)SEQ * QKVN * 2;
  const size_t SZ_X   = (size_t)SEQ * ED * 2;
  const size_t SZ_W   = (size_t)QKVN * ED * 2;
  const size_t SZ_VT  = (size_t)NH * VTROWS * SEQ * 2;
  const size_t NEED   = SZ_QKV + SZ_X + SZ_W + SZ_VT;
  if (ws_size < NEED) return;

  char* ws = (char*)d_ws;
  bf16* qkvbf = (bf16*)(ws);
  bf16* Xbf   = (bf16*)(ws + SZ_QKV);
  bf16* Wbf   = (bf16*)(ws + SZ_QKV + SZ_X);
  bf16* vtb   = (bf16*)(ws + SZ_QKV + SZ_X + SZ_W);

  cvt_f32_bf16<<<(SEQ * ED / 4 + 255) / 256, 256, 0, stream>>>(hidden, Xbf, SEQ * ED / 4);
  cvt_f32_bf16<<<(QKVN * ED / 4 + 255) / 256, 256, 0, stream>>>(qkv_w, Wbf, QKVN * ED / 4);

  gemm_bt<<<(SEQ / 128) * (QKVN / 128), 256, 0, stream>>>(Xbf, Wbf, qkv_b, qkvbf,
                                                          SEQ, QKVN, ED, 1);

  cvt_f32_bf16<<<(ED * ED / 4 + 255) / 256, 256, 0, stream>>>(out_w, Wbf, ED * ED / 4);

  rope_inplace<<<SEQ, 256, 0, stream>>>(qkvbf, rope);

  transpose_v<<<NH * (SEQ / 64), 256, 0, stream>>>(qkvbf, vtb);

  attn<<<NSEG * NH * (SEGLEN / 256), 512, 0, stream>>>(qkvbf, vtb, Xbf);

  gemm_bt<<<(SEQ / 128) * (ED / 128), 256, 0, stream>>>(Xbf, Wbf, out_b, d_out,
                                                        SEQ, ED, ED, 0);
}

// Round 25
// 506.710 us; speedup vs baseline: 1.8665x; 1.0189x over previous
//
#include <hip/hip_runtime.h>
#include <hip/hip_bf16.h>
#include <cstdint>

#define SEQ   16384
#define ED    1152
#define NH    16
#define HD    72
#define NSEG  8
#define SEGLEN 2048
#define QKVN  3456
#define NT    (SEGLEN / 64)
#define VTROWS 80
#define KSZ   (64 * 72)
#define VSZ   (VTROWS * 64)

typedef __bf16 bf16x8 __attribute__((ext_vector_type(8)));
typedef float  f32x4  __attribute__((ext_vector_type(4)));
typedef __hip_bfloat16 bf16;

__device__ __forceinline__ unsigned short f2bfbits(float f) {
  bf16 h = __float2bfloat16(f);
  return __builtin_bit_cast(unsigned short, h);
}

__device__ __forceinline__ float fexp2(float x) {
#if __has_builtin(__builtin_amdgcn_exp2f)
  return __builtin_amdgcn_exp2f(x);
#else
  return exp2f(x);
#endif
}

// round-half-up f32->bf16 (2 VALU); valid for finite positive p (never NaN here)
__device__ __forceinline__ unsigned short f2bf_rhu(float f) {
  unsigned int b = __builtin_bit_cast(unsigned int, f);
  return (unsigned short)((b + 0x8000u) >> 16);
}

__device__ __forceinline__ void gload_lds16(const void* g, void* l) {
  __builtin_amdgcn_global_load_lds(
      (__attribute__((address_space(1))) void*)(void*)g,
      (__attribute__((address_space(3))) void*)l, 16, 0, 0);
}

// ---------------- combined f32->bf16 conversion (hidden + qkv_w + out_w) ----------------
#define N4_HID (SEQ * ED / 4)
#define N4_QW  (QKVN * ED / 4)
#define N4_OW  (ED * ED / 4)
__global__ __launch_bounds__(256) void cvt_all(const float* __restrict__ hidden,
                                               const float* __restrict__ qkv_w,
                                               const float* __restrict__ out_w,
                                               bf16* __restrict__ Xbf,
                                               bf16* __restrict__ Wbf,
                                               bf16* __restrict__ OWbf) {
  int i = blockIdx.x * 256 + threadIdx.x;
  const float* src;
  bf16* dst;
  int j;
  if (i < N4_HID) {
    src = hidden; dst = Xbf; j = i;
  } else if (i < N4_HID + N4_QW) {
    src = qkv_w; dst = Wbf; j = i - N4_HID;
  } else if (i < N4_HID + N4_QW + N4_OW) {
    src = out_w; dst = OWbf; j = i - N4_HID - N4_QW;
  } else {
    return;
  }
  float4 v = reinterpret_cast<const float4*>(src)[j];
  ushort4 o;
  o.x = f2bfbits(v.x); o.y = f2bfbits(v.y); o.z = f2bfbits(v.z); o.w = f2bfbits(v.w);
  reinterpret_cast<ushort4*>(dst)[j] = o;
}

// ---------------- GEMM: C[M][N] = A[M][K]*B[N][K]^T + bias (BK=64, R20-verified) ----
__global__ __launch_bounds__(256) void gemm_bt(const bf16* __restrict__ A,
                                               const bf16* __restrict__ B,
                                               const float* __restrict__ bias,
                                               void* __restrict__ Cout,
                                               int M, int N, int K, int out_bf16) {
  __shared__ __align__(16) bf16 As[2 * 128 * 32];
  __shared__ __align__(16) bf16 Bs[2 * 128 * 32];
  const int nt   = N >> 7;
  const int nwg  = gridDim.x;
  const int cpx  = nwg >> 3;
  const int bid  = blockIdx.x;
  const int swz  = (bid & 7) * cpx + (bid >> 3);
  const int bm   = swz / nt;
  const int bn   = swz % nt;
  const int tid  = threadIdx.x;
  const int lane = tid & 63;
  const int wave = tid >> 6;
  const int wr   = wave >> 1, wc = wave & 1;

  const bf16* Ab = A + (size_t)(bm * 128) * K;
  const bf16* Bb = B + (size_t)(bn * 128) * K;

  char* AsB = (char*)As;
  char* BsB = (char*)Bs;

  const int row15 = lane & 15;
  const int koff  = (lane >> 4) << 3;
  const int srow  = lane >> 2;
  const int scol  = (lane & 3) << 3;

  f32x4 acc[4][4] = {};

  for (int k0 = 0; k0 < K; k0 += 64) {
#pragma unroll
    for (int i = wave; i < 16; i += 4) {
      const int kk = i >> 3, ib = i & 7;
      gload_lds16(Ab + (size_t)(ib * 16 + srow) * K + k0 + kk * 32 + scol, AsB + i * 1024);
      gload_lds16(Bb + (size_t)(ib * 16 + srow) * K + k0 + kk * 32 + scol, BsB + i * 1024);
    }
    __syncthreads();
#pragma unroll
    for (int kk = 0; kk < 2; ++kk) {
      bf16x8 a[4], b[4];
#pragma unroll
      for (int mi = 0; mi < 4; ++mi)
        a[mi] = *reinterpret_cast<const bf16x8*>(&As[kk * 4096 + (wr * 64 + mi * 16 + row15) * 32 + koff]);
#pragma unroll
      for (int ni = 0; ni < 4; ++ni)
        b[ni] = *reinterpret_cast<const bf16x8*>(&Bs[kk * 4096 + (wc * 64 + ni * 16 + row15) * 32 + koff]);
#pragma unroll
      for (int mi = 0; mi < 4; ++mi)
#pragma unroll
        for (int ni = 0; ni < 4; ++ni)
          acc[mi][ni] = __builtin_amdgcn_mfma_f32_16x16x32_bf16(a[mi], b[ni], acc[mi][ni], 0, 0, 0);
    }
    __syncthreads();
  }

  const int crow = bm * 128 + wr * 64 + (lane >> 4) * 4;
  const int ccol = bn * 128 + wc * 64 + row15;
#pragma unroll
  for (int mi = 0; mi < 4; ++mi)
#pragma unroll
    for (int ni = 0; ni < 4; ++ni) {
      const int col = ccol + ni * 16;
      const float bv = bias[col];
#pragma unroll
      for (int r = 0; r < 4; ++r) {
        const int row = crow + mi * 16 + r;
        float v = acc[mi][ni][r] + bv;
        if (out_bf16)
          reinterpret_cast<bf16*>(Cout)[(size_t)row * N + col] = __float2bfloat16(v);
        else
          reinterpret_cast<float*>(Cout)[(size_t)row * N + col] = v;
      }
    }
}

// ---------------- fused RoPE (blocks 0..SEQ-1) + V transpose (blocks SEQ..) ----------------
// rope touches Q,K columns of qkv; transpose reads V columns -> disjoint, race-free.
__global__ __launch_bounds__(256, 4) void rope_tv(bf16* __restrict__ qkv,
                                                  const float* __restrict__ ang,
                                                  bf16* __restrict__ vt) {
  const int tid = threadIdx.x;
  if (blockIdx.x < SEQ) {
    // ---- RoPE in-place on qkv row s (Q and K sections) ----
    const int s = blockIdx.x;
    bf16* row = qkv + (size_t)s * QKVN;
    for (int i = tid; i < 2 * NH * 36; i += 256) {
      int t   = i / (NH * 36);
      int rem = i - t * (NH * 36);
      int h   = rem / 36;
      int d2  = rem - h * 36;
      float a  = ang[s * 36 + d2];
      float cs = cosf(a), sn = sinf(a);
      bf16* p = row + t * ED + h * HD + d2;
      float x1 = __bfloat162float(p[0]);
      float x2 = __bfloat162float(p[36]);
      p[0]  = __float2bfloat16(x1 * cs - x2 * sn);
      p[36] = __float2bfloat16(x2 * cs + x1 * sn);
    }
    return;
  }
  // ---- V transpose -> global V^T[h][d][s] with per-row bank rotation (R24-verified) ----
  const int blk2 = blockIdx.x - SEQ;
  const int h  = blk2 & 15;
  const int st = blk2 >> 4;
  const int s0 = st * 64;
  __shared__ __align__(16) bf16 Lt[72 * 72];

  const bf16* src = qkv + (size_t)s0 * QKVN + 2 * ED + h * HD;
  for (int c = tid; c < 576; c += 256) {
    int j = c / 9, m9 = c - j * 9;
    int d0 = m9 << 3;
    int jj = (j + (m9 << 3)) & 63;
    bf16x8 v = *reinterpret_cast<const bf16x8*>(src + (size_t)j * QKVN + d0);
    const unsigned short* u = reinterpret_cast<const unsigned short*>(&v);
#pragma unroll
    for (int e = 0; e < 8; ++e)
      Lt[(d0 + e) * 72 + jj] = __builtin_bit_cast(bf16, u[e]);
  }
  __syncthreads();

  bf16x8 ones8, zero8 = {};
  {
    unsigned short ob = f2bfbits(1.0f);
#pragma unroll
    for (int e = 0; e < 8; ++e) ones8[e] = __builtin_bit_cast(__bf16, ob);
  }
  bf16* dst = vt + (size_t)(h * VTROWS) * SEQ + s0;
  for (int c = tid; c < VTROWS * 8; c += 256) {
    int d = c >> 3, sc = c & 7;
    bf16x8 v;
    int og = sc;
    if (d < 72) {
      int col = (((sc + (d >> 3)) << 3)) & 63;
      v = *reinterpret_cast<const bf16x8*>(&Lt[d * 72 + col]);
      og = (sc + (d & 7)) & 7;
    } else {
      v = (d == 72) ? ones8 : zero8;
    }
    *reinterpret_cast<bf16x8*>(dst + (size_t)d * SEQ + (og << 3)) = v;
  }
}

// ---------------- flash attention v20 (R24-verified: dbuf staging, 1 barrier/tile) ----
__global__ __launch_bounds__(512, 4) void attn(const bf16* __restrict__ qkv,
                                               const bf16* __restrict__ vt,
                                               bf16* __restrict__ ctx) {
  const int blk  = blockIdx.x;
  const int qt   = (blk >> 3) & 7;
  const int g    = (((blk >> 6) & 15) << 3) | (blk & 7);
  const int head = g & 15;
  const int seg  = g >> 4;
  const int q0   = seg * SEGLEN + qt * 256;

  const int tid = threadIdx.x, lane = tid & 63, w = tid >> 6;   // w in 0..7
  const int row15 = lane & 15, hi = lane >> 4, koff = hi << 3;

  __shared__ __align__(16) bf16 Ks[2 * KSZ];
  __shared__ __align__(16) bf16 Vt[2 * VSZ];
  __shared__ __align__(16) bf16 Ps[256 * 72];

  const bf16* Qg  = qkv + (size_t)q0 * QKVN + head * HD;
  const bf16* Kg  = qkv + (size_t)(seg * SEGLEN) * QKVN + ED + head * HD;
  const bf16* Vtg = vt + (size_t)(head * VTROWS) * SEQ + seg * SEGLEN;

  const bf16x8 zero8 = {};
  bf16x8 aq[2][3];
#pragma unroll
  for (int m = 0; m < 2; ++m) {
    const bf16* qrow = Qg + (size_t)(w * 32 + m * 16 + row15) * QKVN;
    aq[m][0] = *reinterpret_cast<const bf16x8*>(qrow + koff);
    aq[m][1] = *reinterpret_cast<const bf16x8*>(qrow + 32 + koff);
    aq[m][2] = (hi == 0) ? *reinterpret_cast<const bf16x8*>(qrow + 64) : zero8;
  }

  f32x4 oacc[2][5] = {};
  const float c2 = 0.11785113019775793f * 1.4426950408889634f;  // scale * log2(e)

  auto stage_k = [&](int kt2) {
    const bf16* Kt = Kg + (size_t)kt2 * 64 * QKVN;
    char* KsB = (char*)(Ks + (kt2 & 1) * KSZ);
    for (int gq = w; gq < 9; gq += 8) {
      int chunk = gq * 64 + lane;
      int row = chunk / 9;
      int cc  = chunk - row * 9;
      gload_lds16(Kt + (size_t)row * QKVN + cc * 8, KsB + gq * 1024);
    }
  };

  auto stage_v = [&](int kt2) {
    const bf16* Vsrc = Vtg + (size_t)kt2 * 64;
    char* VsB = (char*)(Vt + (kt2 & 1) * VSZ);
    for (int i = w; i < 10; i += 8) {
      int c = i * 64 + lane;
      int d = c >> 3, g8 = c & 7;
      gload_lds16(Vsrc + (size_t)d * SEQ + g8 * 8, VsB + i * 1024);
    }
  };

  auto qkt_soft = [&](int sel) {
    const bf16* ks = Ks + sel * KSZ;
    f32x4 s[2][4] = {};
    __builtin_amdgcn_s_setprio(1);
#pragma unroll
    for (int kc = 0; kc < 2; ++kc) {
#pragma unroll
      for (int n = 0; n < 4; ++n) {
        bf16x8 bk = *reinterpret_cast<const bf16x8*>(&ks[(n * 16 + row15) * 72 + kc * 32 + koff]);
        s[0][n] = __builtin_amdgcn_mfma_f32_16x16x32_bf16(aq[0][kc], bk, s[0][n], 0, 0, 0);
        s[1][n] = __builtin_amdgcn_mfma_f32_16x16x32_bf16(aq[1][kc], bk, s[1][n], 0, 0, 0);
      }
    }
#pragma unroll
    for (int n = 0; n < 4; ++n) {
      bf16x8 bk = (hi == 0) ? *reinterpret_cast<const bf16x8*>(&ks[(n * 16 + row15) * 72 + 64]) : zero8;
      s[0][n] = __builtin_amdgcn_mfma_f32_16x16x32_bf16(aq[0][2], bk, s[0][n], 0, 0, 0);
      s[1][n] = __builtin_amdgcn_mfma_f32_16x16x32_bf16(aq[1][2], bk, s[1][n], 0, 0, 0);
    }
    __builtin_amdgcn_s_setprio(0);
    const int prow_base = w * 32 + hi * 4;
#pragma unroll
    for (int m = 0; m < 2; ++m)
#pragma unroll
      for (int n = 0; n < 4; ++n)
#pragma unroll
        for (int r = 0; r < 4; ++r) {
          float p = fexp2(fmaf(s[m][n][r], c2, -4.0f));
          Ps[(prow_base + m * 16 + r) * 72 + n * 16 + row15] =
              __builtin_bit_cast(bf16, f2bf_rhu(p));
        }
  };

  auto pv = [&](int sel) {
    const bf16* vb = Vt + sel * VSZ;
    __builtin_amdgcn_s_setprio(1);
#pragma unroll
    for (int ks2 = 0; ks2 < 2; ++ks2) {
      bf16x8 ap0 = *reinterpret_cast<const bf16x8*>(&Ps[(w * 32 + row15) * 72 + ks2 * 32 + koff]);
      bf16x8 ap1 = *reinterpret_cast<const bf16x8*>(&Ps[(w * 32 + 16 + row15) * 72 + ks2 * 32 + koff]);
#pragma unroll
      for (int n = 0; n < 5; ++n) {
        const int vrow = n * 16 + row15;
        const int cA = ((((ks2 << 2) + hi + (vrow & 7)) & 7) << 3);
        bf16x8 bv = *reinterpret_cast<const bf16x8*>(&vb[vrow * 64 + cA]);
        oacc[0][n] = __builtin_amdgcn_mfma_f32_16x16x32_bf16(ap0, bv, oacc[0][n], 0, 0, 0);
        oacc[1][n] = __builtin_amdgcn_mfma_f32_16x16x32_bf16(ap1, bv, oacc[1][n], 0, 0, 0);
      }
    }
    __builtin_amdgcn_s_setprio(0);
  };

  stage_k(0);
  stage_v(0);
  for (int kt = 0; kt < NT; ++kt) {
    __syncthreads();
    if (kt + 1 < NT) {
      stage_k(kt + 1);
      stage_v(kt + 1);
    }
    qkt_soft(kt & 1);
    pv(kt & 1);
  }

#pragma unroll
  for (int m = 0; m < 2; ++m) {
#pragma unroll
    for (int r = 0; r < 4; ++r) {
      float l = __shfl(oacc[m][4][r], (lane & 48) + 8);
      float inv = 1.0f / l;
#pragma unroll
      for (int n = 0; n < 5; ++n) {
        const int d = n * 16 + row15;
        if (d < HD) {
          const int row = q0 + w * 32 + m * 16 + hi * 4 + r;
          ctx[(size_t)row * ED + head * HD + d] = __float2bfloat16(oacc[m][n][r] * inv);
        }
      }
    }
  }
}

// ---------------- launch ----------------
extern "C" void kernel_launch(void* const* d_in, const int* in_sizes, int n_in,
                              void* d_out, int out_size, void* d_ws, size_t ws_size,
                              hipStream_t stream) {
  const float* hidden = (const float*)d_in[0];
  const float* qkv_w  = (const float*)d_in[1];
  const float* qkv_b  = (const float*)d_in[2];
  const float* out_w  = (const float*)d_in[3];
  const float* out_b  = (const float*)d_in[4];
  const float* rope   = (const float*)d_in[5];

  const size_t SZ_QKV = (size_t)SEQ * QKVN * 2;
  const size_t SZ_X   = (size_t)SEQ * ED * 2;
  const size_t SZ_W   = (size_t)QKVN * ED * 2;
  const size_t SZ_OW  = (size_t)ED * ED * 2;
  const size_t SZ_VT  = (size_t)NH * VTROWS * SEQ * 2;
  const size_t NEED   = SZ_QKV + SZ_X + SZ_W + SZ_OW + SZ_VT;
  if (ws_size < NEED) return;

  char* ws = (char*)d_ws;
  bf16* qkvbf = (bf16*)(ws);
  bf16* Xbf   = (bf16*)(ws + SZ_QKV);
  bf16* Wbf   = (bf16*)(ws + SZ_QKV + SZ_X);
  bf16* OWbf  = (bf16*)(ws + SZ_QKV + SZ_X + SZ_W);
  bf16* vtb   = (bf16*)(ws + SZ_QKV + SZ_X + SZ_W + SZ_OW);

  const int n4_total = N4_HID + N4_QW + N4_OW;
  cvt_all<<<(n4_total + 255) / 256, 256, 0, stream>>>(hidden, qkv_w, out_w,
                                                      Xbf, Wbf, OWbf);

  gemm_bt<<<(SEQ / 128) * (QKVN / 128), 256, 0, stream>>>(Xbf, Wbf, qkv_b, qkvbf,
                                                          SEQ, QKVN, ED, 1);

  rope_tv<<<SEQ + NH * (SEQ / 64), 256, 0, stream>>>(qkvbf, rope, vtb);

  attn<<<NSEG * NH * (SEGLEN / 256), 512, 0, stream>>>(qkvbf, vtb, Xbf);

  gemm_bt<<<(SEQ / 128) * (ED / 128), 256, 0, stream>>>(Xbf, OWbf, out_b, d_out,
                                                        SEQ, ED, ED, 0);
}